// Round 14
// baseline (128.988 us; speedup 1.0000x reference)
//
#include <hip/hip_runtime.h>
#include <hip/hip_bf16.h>

// C = triu( triu(A) @ triu(B) ), N=4096, fp32 in/out.
// Pass 1 (prep): zero strictly-lower 128-tiles of C + convert fp32->bf16 into
// TILED FRAGMENT-ORDER 128x32 subtiles in d_ws ([g:4][row:128][16B]) +
// an 8KB zero page.
// Pass 2 (main): 256x256 tiles (136 blocks, 512 thr, longest-K first) --
// halves staging bytes/FLOP vs 128^2 (32KB/step for 4 subtiles). 3-buffer
// LDS (96KB) + counted vmcnt(4) 2-deep pipeline, global_load_lds staging,
// 32 MFMA + 12 ds_read_b128 per wave-step, direct masked stores. Zero page
// feeds the A-bottom panel (first 4 steps) / B-left panel (last 4 steps)
// where triu gives all-zero subtiles.

#define NDIM 4096
#define SUBT_B 8192                        // one 128x32 bf16 subtile
#define NSUBT 2112                         // packed subtiles per matrix
#define WS_A ((size_t)NSUBT * SUBT_B)      // 17,301,504
#define WS_TOTAL (2 * WS_A)                // 34,603,008
#define ZOFF WS_TOTAL                      // 8KB zero page
#define WS_NEED (WS_TOTAL + 8192)
#define NZERO 496                          // strictly-lower 128x128 tiles

typedef __attribute__((ext_vector_type(8))) short short8;
typedef __attribute__((ext_vector_type(4))) float f32x4;

__device__ __forceinline__ unsigned pkbf(float a, float b) {
    __hip_bfloat162 h = __float22bfloat162_rn(make_float2(a, b));
    unsigned r;
    __builtin_memcpy(&r, &h, sizeof(r));
    return r;
}

__device__ __forceinline__ void gll16(const void* g, void* l) {
    __builtin_amdgcn_global_load_lds(
        (const __attribute__((address_space(1))) unsigned int*)g,
        (__attribute__((address_space(3))) unsigned int*)l, 16, 0, 0);
}

__device__ __forceinline__ int offA(int p) { return 130 * p - 2 * p * p; }
__device__ __forceinline__ int offB(int q) { return 2 * q * (q + 1); }

// ---------------- pass 1: zero lower C tiles + convert/tile A,B + zpage -----
__global__ __launch_bounds__(256) void prep_kernel(
    const float* __restrict__ A, const float* __restrict__ B,
    float* __restrict__ C, char* __restrict__ ws) {
    const int t = threadIdx.x;
    int b = blockIdx.x;

    if (b < NZERO) {  // ---- zero one strictly-lower 128x128 tile of C ----
        int r = b, p = 1;
        while (r >= p) { r -= p; ++p; }
        const int bi = p, bj = r;          // bj < bi
        const size_t base = (size_t)bi * 128 * NDIM + (size_t)bj * 128;
        const float4 z = make_float4(0.f, 0.f, 0.f, 0.f);
#pragma unroll
        for (int j = 0; j < 16; ++j) {
            const int f = t + 256 * j;
            *reinterpret_cast<float4*>(
                &C[base + (size_t)(f >> 5) * NDIM + (f & 31) * 4]) = z;
        }
        return;
    }
    b -= NZERO;

    if (b < NSUBT) {  // ---- A subtile: [row][k] fp32 -> [g][row][16B] bf16 ----
        int bi = 0, rem = b;
        while (rem >= 128 - 4 * bi) { rem -= 128 - 4 * bi; ++bi; }
        const int kt32 = 4 * bi + rem;

        __shared__ __align__(16) char lsub[SUBT_B];
        const float* src = A + (size_t)(bi * 128) * NDIM + kt32 * 32;
#pragma unroll
        for (int j = 0; j < 4; ++j) {
            const int s4 = t + 256 * j;
            const int row = s4 >> 3;
            const int kf = (s4 & 7) * 4;
            const float4 v =
                *reinterpret_cast<const float4*>(src + (size_t)row * NDIM + kf);
            uint2 w;
            w.x = pkbf(v.x, v.y);
            w.y = pkbf(v.z, v.w);
            *reinterpret_cast<uint2*>(lsub + (kf >> 3) * 2048 + row * 16 +
                                      (kf & 4) * 2) = w;
        }
        __syncthreads();
        char* dst = ws + (size_t)b * SUBT_B;
#pragma unroll
        for (int j = 0; j < 2; ++j) {
            const int d = t + 256 * j;
            *reinterpret_cast<uint4*>(dst + d * 16) =
                *reinterpret_cast<const uint4*>(lsub + d * 16);
        }
        return;
    }
    b -= NSUBT;

    if (b < NSUBT) {  // ---- B subtile: [k][col] fp32 -> [g][col][16B] bf16 ----
        int bj = 0, rem = b;
        while (rem >= 4 * (bj + 1)) { rem -= 4 * (bj + 1); ++bj; }
        const int kt32 = rem;

        const int c = t & 127;
        const int kq = (t >> 7) * 16;
        const float* src = B + (size_t)(kt32 * 32 + kq) * NDIM + bj * 128 + c;
        float v[16];
#pragma unroll
        for (int i = 0; i < 16; ++i) v[i] = src[(size_t)i * NDIM];

        uint4 w0, w1;
        w0.x = pkbf(v[0], v[1]);   w0.y = pkbf(v[2], v[3]);
        w0.z = pkbf(v[4], v[5]);   w0.w = pkbf(v[6], v[7]);
        w1.x = pkbf(v[8], v[9]);   w1.y = pkbf(v[10], v[11]);
        w1.z = pkbf(v[12], v[13]); w1.w = pkbf(v[14], v[15]);

        char* dst = ws + WS_A + (size_t)b * SUBT_B + c * 16;
        const int g0 = kq >> 3;
        *reinterpret_cast<uint4*>(dst + g0 * 2048) = w0;
        *reinterpret_cast<uint4*>(dst + (g0 + 1) * 2048) = w1;
        return;
    }

    {  // ---- 8KB zero page ----
        uint4* zp = reinterpret_cast<uint4*>(ws + ZOFF);
        const uint4 z = {0u, 0u, 0u, 0u};
        zp[t] = z;
        zp[t + 256] = z;
    }
}

// ---------------- pass 2: 256x256 MFMA GEMM, direct stores ------------------
__global__ __launch_bounds__(512) void trimm256_kernel(
    const char* __restrict__ ws, float* __restrict__ C) {
    const int tid = threadIdx.x;

    // decode upper 256-tile, longest k-range first (136 tiles)
    int bi, bj;
    {
        int r = blockIdx.x, L = 16;
        while (r >= 17 - L) { r -= 17 - L; --L; }
        bi = r;
        bj = bi + L - 1;
    }

    const int row0 = bi * 256;
    const int col0 = bj * 256;
    const int nt = 8 * (bj - bi + 1);            // 8..128 BK=32 steps
    const int kt0 = 8 * bi;

    // subtile streams (index advances by t); A1/B0 get the zero page at edges
    const char* srcA0 = ws + (size_t)(offA(2 * bi)) * SUBT_B;           // +t
    const char* srcA1 = ws + (size_t)(offA(2 * bi + 1) - 4) * SUBT_B;   // +t (t>=4)
    const char* srcB0 = ws + WS_A + (size_t)(offB(2 * bj) + kt0) * SUBT_B;
    const char* srcB1 = ws + WS_A + (size_t)(offB(2 * bj + 1) + kt0) * SUBT_B;
    const char* zpage = ws + ZOFF;

    __shared__ __align__(16) char lds[3][4][SUBT_B];   // 96 KB

    f32x4 acc[8][4];
    const f32x4 fz = {0.f, 0.f, 0.f, 0.f};
#pragma unroll
    for (int m = 0; m < 8; ++m)
#pragma unroll
        for (int n = 0; n < 4; ++n) acc[m][n] = fz;

    const int wv = tid >> 6;            // 0..7
    const int wvM = wv >> 2;            // 0..1: row half
    const int wvN = wv & 3;             // 0..3: col quarter
    const int lane = tid & 63;
    const int fr = lane & 15;
    const int gof = (lane >> 4) * 2048; // k-group byte offset
    const int cbase = (wvN & 1) * 64;   // col offset within B panel

    auto stage = [&](int buf, int t) {  // 4 gll16 per thread (one per subtile)
        const char* s0 = srcA0 + (size_t)t * SUBT_B;
        const char* s1 = (t >= 4) ? srcA1 + (size_t)t * SUBT_B : zpage;
        const char* s2 = (t < nt - 4) ? srcB0 + (size_t)t * SUBT_B : zpage;
        const char* s3 = srcB1 + (size_t)t * SUBT_B;
        char* base = &lds[buf][0][0];
        const int lo = wv * 1024 + lane * 16;    // per-lane src offset
        char* d = base + wv * 1024;              // wave-uniform LDS dest
        gll16(s0 + lo, d);
        gll16(s1 + lo, d + SUBT_B);
        gll16(s2 + lo, d + 2 * SUBT_B);
        gll16(s3 + lo, d + 3 * SUBT_B);
    };
    auto compute = [&](int buf) {
        const char* A_ = &lds[buf][wvM][0];
        const char* B_ = &lds[buf][2 + (wvN >> 1)][0];
        short8 af[8], bf[4];
#pragma unroll
        for (int m = 0; m < 8; ++m)
            af[m] = *reinterpret_cast<const short8*>(
                A_ + gof + (m * 16 + fr) * 16);
#pragma unroll
        for (int n = 0; n < 4; ++n)
            bf[n] = *reinterpret_cast<const short8*>(
                B_ + gof + (cbase + n * 16 + fr) * 16);
#pragma unroll
        for (int m = 0; m < 8; ++m)
#pragma unroll
            for (int n = 0; n < 4; ++n)
                acc[m][n] = __builtin_amdgcn_mfma_f32_16x16x32_bf16(
                    af[m], bf[n], acc[m][n], 0, 0, 0);
    };

    // ---- 3-buffer pipeline, counted vmcnt: wait on loads issued 2 steps ago
    stage(0, 0);
    stage(1, 1);                                  // nt >= 8 always
    for (int t = 0; t < nt; ++t) {
        if (t + 1 < nt)
            asm volatile("s_waitcnt vmcnt(4)" ::: "memory");
        else
            asm volatile("s_waitcnt vmcnt(0)" ::: "memory");
        __builtin_amdgcn_s_barrier();
        if (t + 2 < nt) stage((t + 2) % 3, t + 2);
        compute(t % 3);
    }

    // ---- epilogue: direct masked stores ----
    // C/D layout: col=lane&15, row=(lane>>4)*4+reg
#pragma unroll
    for (int m = 0; m < 8; ++m) {
        const int rbase = row0 + wvM * 128 + m * 16 + (lane >> 4) * 4;
#pragma unroll
        for (int n = 0; n < 4; ++n) {
            const int col = col0 + wvN * 64 + n * 16 + fr;
#pragma unroll
            for (int r = 0; r < 4; ++r) {
                const int row = rbase + r;
                C[(size_t)row * NDIM + col] = (row <= col) ? acc[m][n][r] : 0.f;
            }
        }
    }
}

// ---------------- fallback (proven R3 kernel, no workspace) ----------------
#define FLSTR 80
#define NBLK 32
__device__ __forceinline__ int floff(int row, int kb) { return row * FLSTR + kb; }

__global__ __launch_bounds__(256) void trimm_fallback_kernel(
    const float* __restrict__ A, const float* __restrict__ B,
    float* __restrict__ C) {
    const int tid = threadIdx.x;
    const int id = blockIdx.x;
    int bi, bj;
    if (id >= 528) {
        int r = id - 528;
        int p = 1;
        while (r >= p) { r -= p; ++p; }
        bi = p; bj = r;
        const size_t base = (size_t)bi * 128 * NDIM + (size_t)bj * 128;
        const float4 z = make_float4(0.f, 0.f, 0.f, 0.f);
#pragma unroll
        for (int t = 0; t < 16; ++t) {
            const int f = tid + 256 * t;
            *reinterpret_cast<float4*>(
                &C[base + (size_t)(f >> 5) * NDIM + (f & 31) * 4]) = z;
        }
        return;
    }
    {
        int r = id, L = NBLK;
        while (r >= NBLK + 1 - L) { r -= NBLK + 1 - L; --L; }
        bi = r; bj = bi + L - 1;
    }
    const int row0 = bi * 128, col0 = bj * 128;
    __shared__ __align__(16) char lAs[128 * FLSTR];
    __shared__ __align__(16) char lBs[128 * FLSTR];
    f32x4 acc[4][4];
    const f32x4 fz = {0.f, 0.f, 0.f, 0.f};
#pragma unroll
    for (int m = 0; m < 4; ++m)
#pragma unroll
        for (int n = 0; n < 4; ++n) acc[m][n] = fz;
    const int wv = tid >> 6, wr = (wv >> 1) * 64, wc = (wv & 1) * 64;
    const int lane = tid & 63, fr = lane & 15, kb = (lane >> 4) * 16;
    const int bn = tid & 127, bkh = (tid >> 7) * 16;
    const int kendf = col0 + 128;
    for (int kt = row0; kt < kendf; kt += 32) {
        __syncthreads();
#pragma unroll
        for (int j = 0; j < 4; ++j) {
            const int f = tid + 256 * j;
            const int rr = f >> 3, kq = (f & 7) * 4;
            const float4 v = *reinterpret_cast<const float4*>(
                &A[(size_t)(row0 + rr) * NDIM + kt + kq]);
            uint2 w;
            w.x = pkbf(v.x, v.y); w.y = pkbf(v.z, v.w);
            *reinterpret_cast<uint2*>(lAs + floff(rr, kq * 2)) = w;
        }
        {
            float tv[16];
#pragma unroll
            for (int kk = 0; kk < 16; ++kk)
                tv[kk] = B[(size_t)(kt + bkh + kk) * NDIM + col0 + bn];
            uint4 w0, w1;
            w0.x = pkbf(tv[0], tv[1]);   w0.y = pkbf(tv[2], tv[3]);
            w0.z = pkbf(tv[4], tv[5]);   w0.w = pkbf(tv[6], tv[7]);
            w1.x = pkbf(tv[8], tv[9]);   w1.y = pkbf(tv[10], tv[11]);
            w1.z = pkbf(tv[12], tv[13]); w1.w = pkbf(tv[14], tv[15]);
            *reinterpret_cast<uint4*>(lBs + floff(bn, bkh * 2)) = w0;
            *reinterpret_cast<uint4*>(lBs + floff(bn, bkh * 2 + 16)) = w1;
        }
        __syncthreads();
        short8 af[4], bf[4];
#pragma unroll
        for (int m = 0; m < 4; ++m)
            af[m] = *reinterpret_cast<const short8*>(
                lAs + floff(wr + m * 16 + fr, kb));
#pragma unroll
        for (int n = 0; n < 4; ++n)
            bf[n] = *reinterpret_cast<const short8*>(
                lBs + floff(wc + n * 16 + fr, kb));
#pragma unroll
        for (int m = 0; m < 4; ++m)
#pragma unroll
            for (int n = 0; n < 4; ++n)
                acc[m][n] = __builtin_amdgcn_mfma_f32_16x16x32_bf16(
                    af[m], bf[n], acc[m][n], 0, 0, 0);
    }
#pragma unroll
    for (int m = 0; m < 4; ++m) {
        const int rbase = row0 + wr + m * 16 + (lane >> 4) * 4;
#pragma unroll
        for (int n = 0; n < 4; ++n) {
            const int col = col0 + wc + n * 16 + fr;
#pragma unroll
            for (int r = 0; r < 4; ++r) {
                const int row = rbase + r;
                C[(size_t)row * NDIM + col] = (row <= col) ? acc[m][n][r] : 0.f;
            }
        }
    }
}

extern "C" void kernel_launch(void* const* d_in, const int* in_sizes, int n_in,
                              void* d_out, int out_size, void* d_ws,
                              size_t ws_size, hipStream_t stream) {
    const float* A = (const float*)d_in[0];
    const float* B = (const float*)d_in[1];
    float* C = (float*)d_out;
    if (ws_size >= WS_NEED) {
        char* ws = (char*)d_ws;
        prep_kernel<<<dim3(NZERO + 2 * NSUBT + 1), dim3(256), 0, stream>>>(
            A, B, C, ws);
        trimm256_kernel<<<dim3(136), dim3(512), 0, stream>>>(ws, C);
    } else {
        trimm_fallback_kernel<<<dim3(1024), dim3(256), 0, stream>>>(A, B, C);
    }
}

// Round 15
// 100.267 us; speedup vs baseline: 1.2865x; 1.2865x over previous
//
#include <hip/hip_runtime.h>
#include <hip/hip_bf16.h>

// C = triu( triu(A) @ triu(B) ), N=4096, fp32 in/out.
// Pass 1 (prep): zero strictly-lower 128-tiles of C + convert fp32->bf16 into
// TILED FRAGMENT-ORDER 128x32 subtiles in d_ws + 8KB zero page.
// Pass 2 (main): 256x256 tiles; each tile's K split into <=36-step chunks ->
// 248 blocks (all co-resident at 1 block/CU, chains <=36 steps). 3-buffer
// LDS (96KB) + counted vmcnt(4) 2-deep pipeline, global_load_lds staging.
// Single-chunk tiles (L<=4): direct masked stores. Split tiles (L>=5):
// bf16 partial tiles in d_ws (plain stores).
// Pass 3 (reduce): 78 blocks sum <=4 bf16 partials -> C (strictly-upper
// tiles, no mask). Deterministic, no atomics.

#define NDIM 4096
#define SUBT_B 8192                        // one 128x32 bf16 subtile
#define NSUBT 2112                         // packed subtiles per matrix
#define WS_A ((size_t)NSUBT * SUBT_B)      // 17,301,504
#define WS_TOTAL (2 * WS_A)                // 34,603,008
#define ZOFF WS_TOTAL                      // 8KB zero page
#define POFF (WS_TOTAL + 8192)             // bf16 partial region
#define NSLOT 190                          // split chunk-blocks
#define PART_B 131072                      // 256x256 bf16 partial tile
#define WS_NEED (POFF + (size_t)NSLOT * PART_B)   // 59,514,880
#define NZERO 496                          // strictly-lower 128x128 tiles
#define NMAIN 248
#define NRED 78
#define CS 36                              // steps per chunk

typedef __attribute__((ext_vector_type(8))) short short8;
typedef __attribute__((ext_vector_type(4))) float f32x4;

__device__ __forceinline__ unsigned pkbf(float a, float b) {
    __hip_bfloat162 h = __float22bfloat162_rn(make_float2(a, b));
    unsigned r;
    __builtin_memcpy(&r, &h, sizeof(r));
    return r;
}

__device__ __forceinline__ void gll16(const void* g, void* l) {
    __builtin_amdgcn_global_load_lds(
        (const __attribute__((address_space(1))) unsigned int*)g,
        (__attribute__((address_space(3))) unsigned int*)l, 16, 0, 0);
}

__device__ __forceinline__ int offA(int p) { return 130 * p - 2 * p * p; }
__device__ __forceinline__ int offB(int q) { return 2 * q * (q + 1); }

// ---------------- pass 1: zero lower C tiles + convert/tile A,B + zpage -----
__global__ __launch_bounds__(256) void prep_kernel(
    const float* __restrict__ A, const float* __restrict__ B,
    float* __restrict__ C, char* __restrict__ ws) {
    const int t = threadIdx.x;
    int b = blockIdx.x;

    if (b < NZERO) {  // ---- zero one strictly-lower 128x128 tile of C ----
        int r = b, p = 1;
        while (r >= p) { r -= p; ++p; }
        const int bi = p, bj = r;          // bj < bi
        const size_t base = (size_t)bi * 128 * NDIM + (size_t)bj * 128;
        const float4 z = make_float4(0.f, 0.f, 0.f, 0.f);
#pragma unroll
        for (int j = 0; j < 16; ++j) {
            const int f = t + 256 * j;
            *reinterpret_cast<float4*>(
                &C[base + (size_t)(f >> 5) * NDIM + (f & 31) * 4]) = z;
        }
        return;
    }
    b -= NZERO;

    if (b < NSUBT) {  // ---- A subtile: [row][k] fp32 -> [g][row][16B] bf16 ----
        int bi = 0, rem = b;
        while (rem >= 128 - 4 * bi) { rem -= 128 - 4 * bi; ++bi; }
        const int kt32 = 4 * bi + rem;

        __shared__ __align__(16) char lsub[SUBT_B];
        const float* src = A + (size_t)(bi * 128) * NDIM + kt32 * 32;
#pragma unroll
        for (int j = 0; j < 4; ++j) {
            const int s4 = t + 256 * j;
            const int row = s4 >> 3;
            const int kf = (s4 & 7) * 4;
            const float4 v =
                *reinterpret_cast<const float4*>(src + (size_t)row * NDIM + kf);
            uint2 w;
            w.x = pkbf(v.x, v.y);
            w.y = pkbf(v.z, v.w);
            *reinterpret_cast<uint2*>(lsub + (kf >> 3) * 2048 + row * 16 +
                                      (kf & 4) * 2) = w;
        }
        __syncthreads();
        char* dst = ws + (size_t)b * SUBT_B;
#pragma unroll
        for (int j = 0; j < 2; ++j) {
            const int d = t + 256 * j;
            *reinterpret_cast<uint4*>(dst + d * 16) =
                *reinterpret_cast<const uint4*>(lsub + d * 16);
        }
        return;
    }
    b -= NSUBT;

    if (b < NSUBT) {  // ---- B subtile: [k][col] fp32 -> [g][col][16B] bf16 ----
        int bj = 0, rem = b;
        while (rem >= 4 * (bj + 1)) { rem -= 4 * (bj + 1); ++bj; }
        const int kt32 = rem;

        const int c = t & 127;
        const int kq = (t >> 7) * 16;
        const float* src = B + (size_t)(kt32 * 32 + kq) * NDIM + bj * 128 + c;
        float v[16];
#pragma unroll
        for (int i = 0; i < 16; ++i) v[i] = src[(size_t)i * NDIM];

        uint4 w0, w1;
        w0.x = pkbf(v[0], v[1]);   w0.y = pkbf(v[2], v[3]);
        w0.z = pkbf(v[4], v[5]);   w0.w = pkbf(v[6], v[7]);
        w1.x = pkbf(v[8], v[9]);   w1.y = pkbf(v[10], v[11]);
        w1.z = pkbf(v[12], v[13]); w1.w = pkbf(v[14], v[15]);

        char* dst = ws + WS_A + (size_t)b * SUBT_B + c * 16;
        const int g0 = kq >> 3;
        *reinterpret_cast<uint4*>(dst + g0 * 2048) = w0;
        *reinterpret_cast<uint4*>(dst + (g0 + 1) * 2048) = w1;
        return;
    }

    {  // ---- 8KB zero page ----
        uint4* zp = reinterpret_cast<uint4*>(ws + ZOFF);
        const uint4 z = {0u, 0u, 0u, 0u};
        zp[t] = z;
        zp[t + 256] = z;
    }
}

// ---------------- pass 2: 256x256 MFMA GEMM, chunked K ---------------------
__global__ __launch_bounds__(512) void trimm256_kernel(
    const char* __restrict__ ws, float* __restrict__ C,
    char* __restrict__ part) {
    const int tid = threadIdx.x;

    // decode (L desc, bi asc, ch asc): split chunks (L>=5) are ids 0..189
    int bi, bj, ch, cpt;
    {
        int r = blockIdx.x;
        int L = 16;
        for (;; --L) {
            cpt = (8 * L + CS - 1) / CS;
            const int cnt = (17 - L) * cpt;
            if (r < cnt) { bi = r / cpt; ch = r % cpt; break; }
            r -= cnt;
        }
        bj = bi + L - 1;
    }

    const int row0 = bi * 256;
    const int col0 = bj * 256;
    const int ntt = 8 * (bj - bi + 1);           // total steps for the tile
    const int g0 = ch * CS;
    const int nt = min(CS, ntt - g0);            // 4..36 steps this chunk
    const bool direct = (cpt == 1);

    // subtile streams indexed by GLOBAL step g; zero page at triu edges
    const char* srcA0 = ws + (size_t)(offA(2 * bi)) * SUBT_B;
    const char* srcA1 = ws + (size_t)(offA(2 * bi + 1) - 4) * SUBT_B;
    const char* srcB0 = ws + WS_A + (size_t)(offB(2 * bj) + 8 * bi) * SUBT_B;
    const char* srcB1 = ws + WS_A + (size_t)(offB(2 * bj + 1) + 8 * bi) * SUBT_B;
    const char* zpage = ws + ZOFF;

    __shared__ __align__(16) char lds[3][4][SUBT_B];   // 96 KB

    f32x4 acc[8][4];
    const f32x4 fz = {0.f, 0.f, 0.f, 0.f};
#pragma unroll
    for (int m = 0; m < 8; ++m)
#pragma unroll
        for (int n = 0; n < 4; ++n) acc[m][n] = fz;

    const int wv = tid >> 6;            // 0..7
    const int wvM = wv >> 2;            // 0..1: row half
    const int wvN = wv & 3;             // 0..3: col quarter
    const int lane = tid & 63;
    const int fr = lane & 15;
    const int gof = (lane >> 4) * 2048;
    const int cbase = (wvN & 1) * 64;

    auto stage = [&](int buf, int g) {  // 4 gll16 per thread
        const char* s0 = srcA0 + (size_t)g * SUBT_B;
        const char* s1 = (g >= 4) ? srcA1 + (size_t)g * SUBT_B : zpage;
        const char* s2 = (g < ntt - 4) ? srcB0 + (size_t)g * SUBT_B : zpage;
        const char* s3 = srcB1 + (size_t)g * SUBT_B;
        const int lo = wv * 1024 + lane * 16;
        char* d = &lds[buf][0][0] + wv * 1024;
        gll16(s0 + lo, d);
        gll16(s1 + lo, d + SUBT_B);
        gll16(s2 + lo, d + 2 * SUBT_B);
        gll16(s3 + lo, d + 3 * SUBT_B);
    };
    auto compute = [&](int buf) {
        const char* A_ = &lds[buf][wvM][0];
        const char* B_ = &lds[buf][2 + (wvN >> 1)][0];
        short8 af[8], bf[4];
#pragma unroll
        for (int m = 0; m < 8; ++m)
            af[m] = *reinterpret_cast<const short8*>(
                A_ + gof + (m * 16 + fr) * 16);
#pragma unroll
        for (int n = 0; n < 4; ++n)
            bf[n] = *reinterpret_cast<const short8*>(
                B_ + gof + (cbase + n * 16 + fr) * 16);
#pragma unroll
        for (int m = 0; m < 8; ++m)
#pragma unroll
            for (int n = 0; n < 4; ++n)
                acc[m][n] = __builtin_amdgcn_mfma_f32_16x16x32_bf16(
                    af[m], bf[n], acc[m][n], 0, 0, 0);
    };

    stage(0, g0);
    stage(1, g0 + 1);                             // nt >= 4 always
    for (int t = 0; t < nt; ++t) {
        if (t + 1 < nt)
            asm volatile("s_waitcnt vmcnt(4)" ::: "memory");
        else
            asm volatile("s_waitcnt vmcnt(0)" ::: "memory");
        __builtin_amdgcn_s_barrier();
        if (t + 2 < nt) stage((t + 2) % 3, g0 + t + 2);
        compute(t % 3);
    }

    if (direct) {
        // ---- direct masked store (tile may touch the diagonal) ----
#pragma unroll
        for (int m = 0; m < 8; ++m) {
            const int rbase = row0 + wvM * 128 + m * 16 + (lane >> 4) * 4;
#pragma unroll
            for (int n = 0; n < 4; ++n) {
                const int col = col0 + wvN * 64 + n * 16 + fr;
#pragma unroll
                for (int r = 0; r < 4; ++r) {
                    const int row = rbase + r;
                    C[(size_t)row * NDIM + col] =
                        (row <= col) ? acc[m][n][r] : 0.f;
                }
            }
        }
    } else {
        // ---- bf16 partial tile, row-major [256][256], slot = blockIdx ----
        char* po = part + (size_t)blockIdx.x * PART_B;
#pragma unroll
        for (int m = 0; m < 8; ++m) {
            const int rl = wvM * 128 + m * 16 + (lane >> 4) * 4;
#pragma unroll
            for (int n = 0; n < 4; ++n) {
                const int cl = wvN * 64 + n * 16 + fr;
#pragma unroll
                for (int r = 0; r < 4; ++r) {
                    const unsigned short us =
                        (unsigned short)(pkbf(acc[m][n][r], 0.f) & 0xffffu);
                    *reinterpret_cast<unsigned short*>(
                        po + (size_t)((rl + r) * 256 + cl) * 2) = us;
                }
            }
        }
    }
}

// ---------------- pass 3: sum bf16 partials -> C (split tiles) --------------
__global__ __launch_bounds__(256) void reduce_kernel(
    const char* __restrict__ part, float* __restrict__ C) {
    const int t = threadIdx.x;
    int bi, L, slot0, cpt;
    {
        int r = blockIdx.x, sbase = 0;
        for (L = 16;; --L) {
            cpt = (8 * L + CS - 1) / CS;
            const int cnt = 17 - L;              // tiles at this L (all split)
            if (r < cnt) { bi = r; slot0 = sbase + r * cpt; break; }
            sbase += cnt * cpt;
            r -= cnt;
        }
    }
    const int bj = bi + L - 1;                   // L>=5 -> strictly upper
    const int row0 = bi * 256;
    const int col0 = bj * 256;

    for (int j = 0; j < 32; ++j) {
        const int e8 = j * 256 + t;              // 8-elem group id 0..8191
        float s[8];
#pragma unroll
        for (int k = 0; k < 8; ++k) s[k] = 0.f;
        for (int c = 0; c < cpt; ++c) {
            const short8 v = *reinterpret_cast<const short8*>(
                part + (size_t)(slot0 + c) * PART_B + (size_t)e8 * 16);
#pragma unroll
            for (int k = 0; k < 8; ++k) {
                const unsigned u = ((unsigned)(unsigned short)v[k]) << 16;
                float f;
                __builtin_memcpy(&f, &u, 4);
                s[k] += f;
            }
        }
        const int rr = e8 >> 5;                  // 32 groups per 256-col row
        const int cc = (e8 & 31) * 8;
        float* dst = &C[(size_t)(row0 + rr) * NDIM + col0 + cc];
        *reinterpret_cast<f32x4*>(dst) = *reinterpret_cast<f32x4*>(&s[0]);
        *reinterpret_cast<f32x4*>(dst + 4) = *reinterpret_cast<f32x4*>(&s[4]);
    }
}

// ---------------- fallback (proven R3 kernel, no workspace) ----------------
#define FLSTR 80
#define NBLK 32
__device__ __forceinline__ int floff(int row, int kb) { return row * FLSTR + kb; }

__global__ __launch_bounds__(256) void trimm_fallback_kernel(
    const float* __restrict__ A, const float* __restrict__ B,
    float* __restrict__ C) {
    const int tid = threadIdx.x;
    const int id = blockIdx.x;
    int bi, bj;
    if (id >= 528) {
        int r = id - 528;
        int p = 1;
        while (r >= p) { r -= p; ++p; }
        bi = p; bj = r;
        const size_t base = (size_t)bi * 128 * NDIM + (size_t)bj * 128;
        const float4 z = make_float4(0.f, 0.f, 0.f, 0.f);
#pragma unroll
        for (int t = 0; t < 16; ++t) {
            const int f = tid + 256 * t;
            *reinterpret_cast<float4*>(
                &C[base + (size_t)(f >> 5) * NDIM + (f & 31) * 4]) = z;
        }
        return;
    }
    {
        int r = id, L = NBLK;
        while (r >= NBLK + 1 - L) { r -= NBLK + 1 - L; --L; }
        bi = r; bj = bi + L - 1;
    }
    const int row0 = bi * 128, col0 = bj * 128;
    __shared__ __align__(16) char lAs[128 * FLSTR];
    __shared__ __align__(16) char lBs[128 * FLSTR];
    f32x4 acc[4][4];
    const f32x4 fz = {0.f, 0.f, 0.f, 0.f};
#pragma unroll
    for (int m = 0; m < 4; ++m)
#pragma unroll
        for (int n = 0; n < 4; ++n) acc[m][n] = fz;
    const int wv = tid >> 6, wr = (wv >> 1) * 64, wc = (wv & 1) * 64;
    const int lane = tid & 63, fr = lane & 15, kb = (lane >> 4) * 16;
    const int bn = tid & 127, bkh = (tid >> 7) * 16;
    const int kendf = col0 + 128;
    for (int kt = row0; kt < kendf; kt += 32) {
        __syncthreads();
#pragma unroll
        for (int j = 0; j < 4; ++j) {
            const int f = tid + 256 * j;
            const int rr = f >> 3, kq = (f & 7) * 4;
            const float4 v = *reinterpret_cast<const float4*>(
                &A[(size_t)(row0 + rr) * NDIM + kt + kq]);
            uint2 w;
            w.x = pkbf(v.x, v.y); w.y = pkbf(v.z, v.w);
            *reinterpret_cast<uint2*>(lAs + floff(rr, kq * 2)) = w;
        }
        {
            float tv[16];
#pragma unroll
            for (int kk = 0; kk < 16; ++kk)
                tv[kk] = B[(size_t)(kt + bkh + kk) * NDIM + col0 + bn];
            uint4 w0, w1;
            w0.x = pkbf(tv[0], tv[1]);   w0.y = pkbf(tv[2], tv[3]);
            w0.z = pkbf(tv[4], tv[5]);   w0.w = pkbf(tv[6], tv[7]);
            w1.x = pkbf(tv[8], tv[9]);   w1.y = pkbf(tv[10], tv[11]);
            w1.z = pkbf(tv[12], tv[13]); w1.w = pkbf(tv[14], tv[15]);
            *reinterpret_cast<uint4*>(lBs + floff(bn, bkh * 2)) = w0;
            *reinterpret_cast<uint4*>(lBs + floff(bn, bkh * 2 + 16)) = w1;
        }
        __syncthreads();
        short8 af[4], bf[4];
#pragma unroll
        for (int m = 0; m < 4; ++m)
            af[m] = *reinterpret_cast<const short8*>(
                lAs + floff(wr + m * 16 + fr, kb));
#pragma unroll
        for (int n = 0; n < 4; ++n)
            bf[n] = *reinterpret_cast<const short8*>(
                lBs + floff(wc + n * 16 + fr, kb));
#pragma unroll
        for (int m = 0; m < 4; ++m)
#pragma unroll
            for (int n = 0; n < 4; ++n)
                acc[m][n] = __builtin_amdgcn_mfma_f32_16x16x32_bf16(
                    af[m], bf[n], acc[m][n], 0, 0, 0);
    }
#pragma unroll
    for (int m = 0; m < 4; ++m) {
        const int rbase = row0 + wr + m * 16 + (lane >> 4) * 4;
#pragma unroll
        for (int n = 0; n < 4; ++n) {
            const int col = col0 + wc + n * 16 + fr;
#pragma unroll
            for (int r = 0; r < 4; ++r) {
                const int row = rbase + r;
                C[(size_t)row * NDIM + col] = (row <= col) ? acc[m][n][r] : 0.f;
            }
        }
    }
}

extern "C" void kernel_launch(void* const* d_in, const int* in_sizes, int n_in,
                              void* d_out, int out_size, void* d_ws,
                              size_t ws_size, hipStream_t stream) {
    const float* A = (const float*)d_in[0];
    const float* B = (const float*)d_in[1];
    float* C = (float*)d_out;
    if (ws_size >= WS_NEED) {
        char* ws = (char*)d_ws;
        char* part = ws + POFF;
        prep_kernel<<<dim3(NZERO + 2 * NSUBT + 1), dim3(256), 0, stream>>>(
            A, B, C, ws);
        trimm256_kernel<<<dim3(NMAIN), dim3(512), 0, stream>>>(ws, C, part);
        reduce_kernel<<<dim3(NRED), dim3(256), 0, stream>>>(part, C);
    } else {
        trimm_fallback_kernel<<<dim3(1024), dim3(256), 0, stream>>>(A, B, C);
    }
}

// Round 16
// 68.271 us; speedup vs baseline: 1.8894x; 1.4687x over previous
//
#include <hip/hip_runtime.h>
#include <hip/hip_bf16.h>

// C = triu( triu(A) @ triu(B) ), N=4096, fp32 in/out.
// Pass 1 (prep): zero strictly-lower 128-tiles of C + convert fp32->bf16 into
// TILED FRAGMENT-ORDER 128x32 subtiles in d_ws + 8KB zero page.
// Pass 2 (main): 256x256 tiles; K split into <=36-step chunks -> 248 blocks
// (all co-resident at 1 block/CU). 3-buffer LDS (96KB) + counted vmcnt(4)
// 2-deep pipeline, global_load_lds staging. L<=4 tiles: direct masked
// stores. L>=5 tiles: bf16 partials in d_ws.
// Pass 3 (reduce): 78 tiles x 16 row-stripes = 1248 blocks (R15 had 78 ->
// 1.8% occupancy, 41.7us); static-unrolled cpt in {2,3,4}. ~45MB traffic.

#define NDIM 4096
#define SUBT_B 8192                        // one 128x32 bf16 subtile
#define NSUBT 2112                         // packed subtiles per matrix
#define WS_A ((size_t)NSUBT * SUBT_B)      // 17,301,504
#define WS_TOTAL (2 * WS_A)                // 34,603,008
#define ZOFF WS_TOTAL                      // 8KB zero page
#define POFF (WS_TOTAL + 8192)             // bf16 partial region
#define NSLOT 190                          // split chunk-blocks
#define PART_B 131072                      // 256x256 bf16 partial tile
#define WS_NEED (POFF + (size_t)NSLOT * PART_B)   // 59,514,880
#define NZERO 496                          // strictly-lower 128x128 tiles
#define NMAIN 248
#define NRED 78
#define CS 36                              // steps per chunk

typedef __attribute__((ext_vector_type(8))) short short8;
typedef __attribute__((ext_vector_type(4))) float f32x4;

__device__ __forceinline__ unsigned pkbf(float a, float b) {
    __hip_bfloat162 h = __float22bfloat162_rn(make_float2(a, b));
    unsigned r;
    __builtin_memcpy(&r, &h, sizeof(r));
    return r;
}

__device__ __forceinline__ float bf2f(unsigned short us) {
    const unsigned u = ((unsigned)us) << 16;
    float f;
    __builtin_memcpy(&f, &u, 4);
    return f;
}

__device__ __forceinline__ void gll16(const void* g, void* l) {
    __builtin_amdgcn_global_load_lds(
        (const __attribute__((address_space(1))) unsigned int*)g,
        (__attribute__((address_space(3))) unsigned int*)l, 16, 0, 0);
}

__device__ __forceinline__ int offA(int p) { return 130 * p - 2 * p * p; }
__device__ __forceinline__ int offB(int q) { return 2 * q * (q + 1); }

// ---------------- pass 1: zero lower C tiles + convert/tile A,B + zpage -----
__global__ __launch_bounds__(256) void prep_kernel(
    const float* __restrict__ A, const float* __restrict__ B,
    float* __restrict__ C, char* __restrict__ ws) {
    const int t = threadIdx.x;
    int b = blockIdx.x;

    if (b < NZERO) {  // ---- zero one strictly-lower 128x128 tile of C ----
        int r = b, p = 1;
        while (r >= p) { r -= p; ++p; }
        const int bi = p, bj = r;          // bj < bi
        const size_t base = (size_t)bi * 128 * NDIM + (size_t)bj * 128;
        const float4 z = make_float4(0.f, 0.f, 0.f, 0.f);
#pragma unroll
        for (int j = 0; j < 16; ++j) {
            const int f = t + 256 * j;
            *reinterpret_cast<float4*>(
                &C[base + (size_t)(f >> 5) * NDIM + (f & 31) * 4]) = z;
        }
        return;
    }
    b -= NZERO;

    if (b < NSUBT) {  // ---- A subtile: [row][k] fp32 -> [g][row][16B] bf16 ----
        int bi = 0, rem = b;
        while (rem >= 128 - 4 * bi) { rem -= 128 - 4 * bi; ++bi; }
        const int kt32 = 4 * bi + rem;

        __shared__ __align__(16) char lsub[SUBT_B];
        const float* src = A + (size_t)(bi * 128) * NDIM + kt32 * 32;
#pragma unroll
        for (int j = 0; j < 4; ++j) {
            const int s4 = t + 256 * j;
            const int row = s4 >> 3;
            const int kf = (s4 & 7) * 4;
            const float4 v =
                *reinterpret_cast<const float4*>(src + (size_t)row * NDIM + kf);
            uint2 w;
            w.x = pkbf(v.x, v.y);
            w.y = pkbf(v.z, v.w);
            *reinterpret_cast<uint2*>(lsub + (kf >> 3) * 2048 + row * 16 +
                                      (kf & 4) * 2) = w;
        }
        __syncthreads();
        char* dst = ws + (size_t)b * SUBT_B;
#pragma unroll
        for (int j = 0; j < 2; ++j) {
            const int d = t + 256 * j;
            *reinterpret_cast<uint4*>(dst + d * 16) =
                *reinterpret_cast<const uint4*>(lsub + d * 16);
        }
        return;
    }
    b -= NSUBT;

    if (b < NSUBT) {  // ---- B subtile: [k][col] fp32 -> [g][col][16B] bf16 ----
        int bj = 0, rem = b;
        while (rem >= 4 * (bj + 1)) { rem -= 4 * (bj + 1); ++bj; }
        const int kt32 = rem;

        const int c = t & 127;
        const int kq = (t >> 7) * 16;
        const float* src = B + (size_t)(kt32 * 32 + kq) * NDIM + bj * 128 + c;
        float v[16];
#pragma unroll
        for (int i = 0; i < 16; ++i) v[i] = src[(size_t)i * NDIM];

        uint4 w0, w1;
        w0.x = pkbf(v[0], v[1]);   w0.y = pkbf(v[2], v[3]);
        w0.z = pkbf(v[4], v[5]);   w0.w = pkbf(v[6], v[7]);
        w1.x = pkbf(v[8], v[9]);   w1.y = pkbf(v[10], v[11]);
        w1.z = pkbf(v[12], v[13]); w1.w = pkbf(v[14], v[15]);

        char* dst = ws + WS_A + (size_t)b * SUBT_B + c * 16;
        const int g0 = kq >> 3;
        *reinterpret_cast<uint4*>(dst + g0 * 2048) = w0;
        *reinterpret_cast<uint4*>(dst + (g0 + 1) * 2048) = w1;
        return;
    }

    {  // ---- 8KB zero page ----
        uint4* zp = reinterpret_cast<uint4*>(ws + ZOFF);
        const uint4 z = {0u, 0u, 0u, 0u};
        zp[t] = z;
        zp[t + 256] = z;
    }
}

// ---------------- pass 2: 256x256 MFMA GEMM, chunked K ---------------------
__global__ __launch_bounds__(512) void trimm256_kernel(
    const char* __restrict__ ws, float* __restrict__ C,
    char* __restrict__ part) {
    const int tid = threadIdx.x;

    // decode (L desc, bi asc, ch asc): split chunks (L>=5) are ids 0..189
    int bi, bj, ch, cpt;
    {
        int r = blockIdx.x;
        int L = 16;
        for (;; --L) {
            cpt = (8 * L + CS - 1) / CS;
            const int cnt = (17 - L) * cpt;
            if (r < cnt) { bi = r / cpt; ch = r % cpt; break; }
            r -= cnt;
        }
        bj = bi + L - 1;
    }

    const int row0 = bi * 256;
    const int col0 = bj * 256;
    const int ntt = 8 * (bj - bi + 1);           // total steps for the tile
    const int g0 = ch * CS;
    const int nt = min(CS, ntt - g0);            // 4..36 steps this chunk
    const bool direct = (cpt == 1);

    // subtile streams indexed by GLOBAL step g; zero page at triu edges
    const char* srcA0 = ws + (size_t)(offA(2 * bi)) * SUBT_B;
    const char* srcA1 = ws + (size_t)(offA(2 * bi + 1) - 4) * SUBT_B;
    const char* srcB0 = ws + WS_A + (size_t)(offB(2 * bj) + 8 * bi) * SUBT_B;
    const char* srcB1 = ws + WS_A + (size_t)(offB(2 * bj + 1) + 8 * bi) * SUBT_B;
    const char* zpage = ws + ZOFF;

    __shared__ __align__(16) char lds[3][4][SUBT_B];   // 96 KB

    f32x4 acc[8][4];
    const f32x4 fz = {0.f, 0.f, 0.f, 0.f};
#pragma unroll
    for (int m = 0; m < 8; ++m)
#pragma unroll
        for (int n = 0; n < 4; ++n) acc[m][n] = fz;

    const int wv = tid >> 6;            // 0..7
    const int wvM = wv >> 2;            // 0..1: row half
    const int wvN = wv & 3;             // 0..3: col quarter
    const int lane = tid & 63;
    const int fr = lane & 15;
    const int gof = (lane >> 4) * 2048;
    const int cbase = (wvN & 1) * 64;

    auto stage = [&](int buf, int g) {  // 4 gll16 per thread
        const char* s0 = srcA0 + (size_t)g * SUBT_B;
        const char* s1 = (g >= 4) ? srcA1 + (size_t)g * SUBT_B : zpage;
        const char* s2 = (g < ntt - 4) ? srcB0 + (size_t)g * SUBT_B : zpage;
        const char* s3 = srcB1 + (size_t)g * SUBT_B;
        const int lo = wv * 1024 + lane * 16;
        char* d = &lds[buf][0][0] + wv * 1024;
        gll16(s0 + lo, d);
        gll16(s1 + lo, d + SUBT_B);
        gll16(s2 + lo, d + 2 * SUBT_B);
        gll16(s3 + lo, d + 3 * SUBT_B);
    };
    auto compute = [&](int buf) {
        const char* A_ = &lds[buf][wvM][0];
        const char* B_ = &lds[buf][2 + (wvN >> 1)][0];
        short8 af[8], bf[4];
#pragma unroll
        for (int m = 0; m < 8; ++m)
            af[m] = *reinterpret_cast<const short8*>(
                A_ + gof + (m * 16 + fr) * 16);
#pragma unroll
        for (int n = 0; n < 4; ++n)
            bf[n] = *reinterpret_cast<const short8*>(
                B_ + gof + (cbase + n * 16 + fr) * 16);
#pragma unroll
        for (int m = 0; m < 8; ++m)
#pragma unroll
            for (int n = 0; n < 4; ++n)
                acc[m][n] = __builtin_amdgcn_mfma_f32_16x16x32_bf16(
                    af[m], bf[n], acc[m][n], 0, 0, 0);
    };

    stage(0, g0);
    stage(1, g0 + 1);                             // nt >= 4 always
    for (int t = 0; t < nt; ++t) {
        if (t + 1 < nt)
            asm volatile("s_waitcnt vmcnt(4)" ::: "memory");
        else
            asm volatile("s_waitcnt vmcnt(0)" ::: "memory");
        __builtin_amdgcn_s_barrier();
        if (t + 2 < nt) stage((t + 2) % 3, g0 + t + 2);
        compute(t % 3);
    }

    if (direct) {
        // ---- direct masked store (tile may touch the diagonal) ----
#pragma unroll
        for (int m = 0; m < 8; ++m) {
            const int rbase = row0 + wvM * 128 + m * 16 + (lane >> 4) * 4;
#pragma unroll
            for (int n = 0; n < 4; ++n) {
                const int col = col0 + wvN * 64 + n * 16 + fr;
#pragma unroll
                for (int r = 0; r < 4; ++r) {
                    const int row = rbase + r;
                    C[(size_t)row * NDIM + col] =
                        (row <= col) ? acc[m][n][r] : 0.f;
                }
            }
        }
    } else {
        // ---- bf16 partial tile, row-major [256][256], slot = blockIdx ----
        char* po = part + (size_t)blockIdx.x * PART_B;
#pragma unroll
        for (int m = 0; m < 8; ++m) {
            const int rl = wvM * 128 + m * 16 + (lane >> 4) * 4;
#pragma unroll
            for (int n = 0; n < 4; ++n) {
                const int cl = wvN * 64 + n * 16 + fr;
#pragma unroll
                for (int r = 0; r < 4; ++r) {
                    const unsigned short us =
                        (unsigned short)(pkbf(acc[m][n][r], 0.f) & 0xffffu);
                    *reinterpret_cast<unsigned short*>(
                        po + (size_t)((rl + r) * 256 + cl) * 2) = us;
                }
            }
        }
    }
}

// ------- pass 3: sum bf16 partials -> C (78 tiles x 16 stripes) ------------
__global__ __launch_bounds__(256) void reduce_kernel(
    const char* __restrict__ part, float* __restrict__ C) {
    const int t = threadIdx.x;
    const int tile = blockIdx.x >> 4;            // 0..77
    const int stripe = blockIdx.x & 15;          // 16 rows each
    int bi, L, slot0, cpt;
    {
        int r = tile, sbase = 0;
        for (L = 16;; --L) {
            cpt = (8 * L + CS - 1) / CS;
            const int cnt = 17 - L;              // tiles at this L (all split)
            if (r < cnt) { bi = r; slot0 = sbase + r * cpt; break; }
            sbase += cnt * cpt;
            r -= cnt;
        }
    }
    const int bj = bi + L - 1;                   // L>=5 -> strictly upper
    const int row0 = bi * 256;
    const int col0 = bj * 256;

    const char* p0 = part + (size_t)slot0 * PART_B;
#pragma unroll
    for (int j = 0; j < 2; ++j) {
        const int g = stripe * 512 + j * 256 + t;   // 8-elem group 0..8191
        const size_t go = (size_t)g * 16;
        float s[8];
        // cpt is block-uniform in {2,3,4}; loads issued before the adds
        const short8 v0 = *reinterpret_cast<const short8*>(p0 + go);
        const short8 v1 = *reinterpret_cast<const short8*>(p0 + PART_B + go);
#pragma unroll
        for (int k = 0; k < 8; ++k)
            s[k] = bf2f((unsigned short)v0[k]) + bf2f((unsigned short)v1[k]);
        if (cpt > 2) {
            const short8 v2 =
                *reinterpret_cast<const short8*>(p0 + 2 * PART_B + go);
#pragma unroll
            for (int k = 0; k < 8; ++k) s[k] += bf2f((unsigned short)v2[k]);
        }
        if (cpt > 3) {
            const short8 v3 =
                *reinterpret_cast<const short8*>(p0 + 3 * PART_B + go);
#pragma unroll
            for (int k = 0; k < 8; ++k) s[k] += bf2f((unsigned short)v3[k]);
        }
        const int rr = g >> 5;                   // 32 groups per 256-col row
        const int cc = (g & 31) * 8;
        float* dst = &C[(size_t)(row0 + rr) * NDIM + col0 + cc];
        *reinterpret_cast<f32x4*>(dst) = *reinterpret_cast<const f32x4*>(&s[0]);
        *reinterpret_cast<f32x4*>(dst + 4) =
            *reinterpret_cast<const f32x4*>(&s[4]);
    }
}

// ---------------- fallback (proven R3 kernel, no workspace) ----------------
#define FLSTR 80
#define NBLK 32
__device__ __forceinline__ int floff(int row, int kb) { return row * FLSTR + kb; }

__global__ __launch_bounds__(256) void trimm_fallback_kernel(
    const float* __restrict__ A, const float* __restrict__ B,
    float* __restrict__ C) {
    const int tid = threadIdx.x;
    const int id = blockIdx.x;
    int bi, bj;
    if (id >= 528) {
        int r = id - 528;
        int p = 1;
        while (r >= p) { r -= p; ++p; }
        bi = p; bj = r;
        const size_t base = (size_t)bi * 128 * NDIM + (size_t)bj * 128;
        const float4 z = make_float4(0.f, 0.f, 0.f, 0.f);
#pragma unroll
        for (int t = 0; t < 16; ++t) {
            const int f = tid + 256 * t;
            *reinterpret_cast<float4*>(
                &C[base + (size_t)(f >> 5) * NDIM + (f & 31) * 4]) = z;
        }
        return;
    }
    {
        int r = id, L = NBLK;
        while (r >= NBLK + 1 - L) { r -= NBLK + 1 - L; --L; }
        bi = r; bj = bi + L - 1;
    }
    const int row0 = bi * 128, col0 = bj * 128;
    __shared__ __align__(16) char lAs[128 * FLSTR];
    __shared__ __align__(16) char lBs[128 * FLSTR];
    f32x4 acc[4][4];
    const f32x4 fz = {0.f, 0.f, 0.f, 0.f};
#pragma unroll
    for (int m = 0; m < 4; ++m)
#pragma unroll
        for (int n = 0; n < 4; ++n) acc[m][n] = fz;
    const int wv = tid >> 6, wr = (wv >> 1) * 64, wc = (wv & 1) * 64;
    const int lane = tid & 63, fr = lane & 15, kb = (lane >> 4) * 16;
    const int bn = tid & 127, bkh = (tid >> 7) * 16;
    const int kendf = col0 + 128;
    for (int kt = row0; kt < kendf; kt += 32) {
        __syncthreads();
#pragma unroll
        for (int j = 0; j < 4; ++j) {
            const int f = tid + 256 * j;
            const int rr = f >> 3, kq = (f & 7) * 4;
            const float4 v = *reinterpret_cast<const float4*>(
                &A[(size_t)(row0 + rr) * NDIM + kt + kq]);
            uint2 w;
            w.x = pkbf(v.x, v.y); w.y = pkbf(v.z, v.w);
            *reinterpret_cast<uint2*>(lAs + floff(rr, kq * 2)) = w;
        }
        {
            float tv[16];
#pragma unroll
            for (int kk = 0; kk < 16; ++kk)
                tv[kk] = B[(size_t)(kt + bkh + kk) * NDIM + col0 + bn];
            uint4 w0, w1;
            w0.x = pkbf(tv[0], tv[1]);   w0.y = pkbf(tv[2], tv[3]);
            w0.z = pkbf(tv[4], tv[5]);   w0.w = pkbf(tv[6], tv[7]);
            w1.x = pkbf(tv[8], tv[9]);   w1.y = pkbf(tv[10], tv[11]);
            w1.z = pkbf(tv[12], tv[13]); w1.w = pkbf(tv[14], tv[15]);
            *reinterpret_cast<uint4*>(lBs + floff(bn, bkh * 2)) = w0;
            *reinterpret_cast<uint4*>(lBs + floff(bn, bkh * 2 + 16)) = w1;
        }
        __syncthreads();
        short8 af[4], bf[4];
#pragma unroll
        for (int m = 0; m < 4; ++m)
            af[m] = *reinterpret_cast<const short8*>(
                lAs + floff(wr + m * 16 + fr, kb));
#pragma unroll
        for (int n = 0; n < 4; ++n)
            bf[n] = *reinterpret_cast<const short8*>(
                lBs + floff(wc + n * 16 + fr, kb));
#pragma unroll
        for (int m = 0; m < 4; ++m)
#pragma unroll
            for (int n = 0; n < 4; ++n)
                acc[m][n] = __builtin_amdgcn_mfma_f32_16x16x32_bf16(
                    af[m], bf[n], acc[m][n], 0, 0, 0);
    }
#pragma unroll
    for (int m = 0; m < 4; ++m) {
        const int rbase = row0 + wr + m * 16 + (lane >> 4) * 4;
#pragma unroll
        for (int n = 0; n < 4; ++n) {
            const int col = col0 + wc + n * 16 + fr;
#pragma unroll
            for (int r = 0; r < 4; ++r) {
                const int row = rbase + r;
                C[(size_t)row * NDIM + col] = (row <= col) ? acc[m][n][r] : 0.f;
            }
        }
    }
}

extern "C" void kernel_launch(void* const* d_in, const int* in_sizes, int n_in,
                              void* d_out, int out_size, void* d_ws,
                              size_t ws_size, hipStream_t stream) {
    const float* A = (const float*)d_in[0];
    const float* B = (const float*)d_in[1];
    float* C = (float*)d_out;
    if (ws_size >= WS_NEED) {
        char* ws = (char*)d_ws;
        char* part = ws + POFF;
        prep_kernel<<<dim3(NZERO + 2 * NSUBT + 1), dim3(256), 0, stream>>>(
            A, B, C, ws);
        trimm256_kernel<<<dim3(NMAIN), dim3(512), 0, stream>>>(ws, C, part);
        reduce_kernel<<<dim3(NRED * 16), dim3(256), 0, stream>>>(part, C);
    } else {
        trimm_fallback_kernel<<<dim3(1024), dim3(256), 0, stream>>>(A, B, C);
    }
}

// Round 17
// 66.970 us; speedup vs baseline: 1.9261x; 1.0194x over previous
//
#include <hip/hip_runtime.h>
#include <hip/hip_bf16.h>

// C = triu( triu(A) @ triu(B) ), N=4096, fp32 in/out.
// Pass 1 (prep): zero strictly-lower 128-tiles of C + convert fp32->bf16 into
// TILED FRAGMENT-ORDER 128x32 subtiles in d_ws + 8KB zero page.
// Pass 2 (main): 256x256 tiles; K split into <=36-step chunks -> 248 blocks.
// 4-buffer LDS (128KB) + counted vmcnt(8) 3-deep pipeline (96KB/CU in
// flight), global_load_lds staging, s_setprio around MFMA cluster.
// L<=4 tiles: direct masked stores. L>=5: bf16 partials in d_ws.
// Pass 3 (reduce): 78 tiles x 16 row-stripes = 1248 blocks.

#define NDIM 4096
#define SUBT_B 8192                        // one 128x32 bf16 subtile
#define NSUBT 2112                         // packed subtiles per matrix
#define WS_A ((size_t)NSUBT * SUBT_B)      // 17,301,504
#define WS_TOTAL (2 * WS_A)                // 34,603,008
#define ZOFF WS_TOTAL                      // 8KB zero page
#define POFF (WS_TOTAL + 8192)             // bf16 partial region
#define NSLOT 190                          // split chunk-blocks
#define PART_B 131072                      // 256x256 bf16 partial tile
#define WS_NEED (POFF + (size_t)NSLOT * PART_B)   // 59,514,880
#define NZERO 496                          // strictly-lower 128x128 tiles
#define NMAIN 248
#define NRED 78
#define CS 36                              // steps per chunk

typedef __attribute__((ext_vector_type(8))) short short8;
typedef __attribute__((ext_vector_type(4))) float f32x4;

__device__ __forceinline__ unsigned pkbf(float a, float b) {
    __hip_bfloat162 h = __float22bfloat162_rn(make_float2(a, b));
    unsigned r;
    __builtin_memcpy(&r, &h, sizeof(r));
    return r;
}

__device__ __forceinline__ float bf2f(unsigned short us) {
    const unsigned u = ((unsigned)us) << 16;
    float f;
    __builtin_memcpy(&f, &u, 4);
    return f;
}

__device__ __forceinline__ void gll16(const void* g, void* l) {
    __builtin_amdgcn_global_load_lds(
        (const __attribute__((address_space(1))) unsigned int*)g,
        (__attribute__((address_space(3))) unsigned int*)l, 16, 0, 0);
}

__device__ __forceinline__ int offA(int p) { return 130 * p - 2 * p * p; }
__device__ __forceinline__ int offB(int q) { return 2 * q * (q + 1); }

// ---------------- pass 1: zero lower C tiles + convert/tile A,B + zpage -----
__global__ __launch_bounds__(256) void prep_kernel(
    const float* __restrict__ A, const float* __restrict__ B,
    float* __restrict__ C, char* __restrict__ ws) {
    const int t = threadIdx.x;
    int b = blockIdx.x;

    if (b < NZERO) {  // ---- zero one strictly-lower 128x128 tile of C ----
        int r = b, p = 1;
        while (r >= p) { r -= p; ++p; }
        const int bi = p, bj = r;          // bj < bi
        const size_t base = (size_t)bi * 128 * NDIM + (size_t)bj * 128;
        const float4 z = make_float4(0.f, 0.f, 0.f, 0.f);
#pragma unroll
        for (int j = 0; j < 16; ++j) {
            const int f = t + 256 * j;
            *reinterpret_cast<float4*>(
                &C[base + (size_t)(f >> 5) * NDIM + (f & 31) * 4]) = z;
        }
        return;
    }
    b -= NZERO;

    if (b < NSUBT) {  // ---- A subtile: [row][k] fp32 -> [g][row][16B] bf16 ----
        int bi = 0, rem = b;
        while (rem >= 128 - 4 * bi) { rem -= 128 - 4 * bi; ++bi; }
        const int kt32 = 4 * bi + rem;

        __shared__ __align__(16) char lsub[SUBT_B];
        const float* src = A + (size_t)(bi * 128) * NDIM + kt32 * 32;
#pragma unroll
        for (int j = 0; j < 4; ++j) {
            const int s4 = t + 256 * j;
            const int row = s4 >> 3;
            const int kf = (s4 & 7) * 4;
            const float4 v =
                *reinterpret_cast<const float4*>(src + (size_t)row * NDIM + kf);
            uint2 w;
            w.x = pkbf(v.x, v.y);
            w.y = pkbf(v.z, v.w);
            *reinterpret_cast<uint2*>(lsub + (kf >> 3) * 2048 + row * 16 +
                                      (kf & 4) * 2) = w;
        }
        __syncthreads();
        char* dst = ws + (size_t)b * SUBT_B;
#pragma unroll
        for (int j = 0; j < 2; ++j) {
            const int d = t + 256 * j;
            *reinterpret_cast<uint4*>(dst + d * 16) =
                *reinterpret_cast<const uint4*>(lsub + d * 16);
        }
        return;
    }
    b -= NSUBT;

    if (b < NSUBT) {  // ---- B subtile: [k][col] fp32 -> [g][col][16B] bf16 ----
        int bj = 0, rem = b;
        while (rem >= 4 * (bj + 1)) { rem -= 4 * (bj + 1); ++bj; }
        const int kt32 = rem;

        const int c = t & 127;
        const int kq = (t >> 7) * 16;
        const float* src = B + (size_t)(kt32 * 32 + kq) * NDIM + bj * 128 + c;
        float v[16];
#pragma unroll
        for (int i = 0; i < 16; ++i) v[i] = src[(size_t)i * NDIM];

        uint4 w0, w1;
        w0.x = pkbf(v[0], v[1]);   w0.y = pkbf(v[2], v[3]);
        w0.z = pkbf(v[4], v[5]);   w0.w = pkbf(v[6], v[7]);
        w1.x = pkbf(v[8], v[9]);   w1.y = pkbf(v[10], v[11]);
        w1.z = pkbf(v[12], v[13]); w1.w = pkbf(v[14], v[15]);

        char* dst = ws + WS_A + (size_t)b * SUBT_B + c * 16;
        const int g0 = kq >> 3;
        *reinterpret_cast<uint4*>(dst + g0 * 2048) = w0;
        *reinterpret_cast<uint4*>(dst + (g0 + 1) * 2048) = w1;
        return;
    }

    {  // ---- 8KB zero page ----
        uint4* zp = reinterpret_cast<uint4*>(ws + ZOFF);
        const uint4 z = {0u, 0u, 0u, 0u};
        zp[t] = z;
        zp[t + 256] = z;
    }
}

// ---------------- pass 2: 256x256 MFMA GEMM, chunked K ---------------------
__global__ __launch_bounds__(512) void trimm256_kernel(
    const char* __restrict__ ws, float* __restrict__ C,
    char* __restrict__ part) {
    const int tid = threadIdx.x;

    // decode (L desc, bi asc, ch asc): split chunks (L>=5) are ids 0..189
    int bi, bj, ch, cpt;
    {
        int r = blockIdx.x;
        int L = 16;
        for (;; --L) {
            cpt = (8 * L + CS - 1) / CS;
            const int cnt = (17 - L) * cpt;
            if (r < cnt) { bi = r / cpt; ch = r % cpt; break; }
            r -= cnt;
        }
        bj = bi + L - 1;
    }

    const int row0 = bi * 256;
    const int col0 = bj * 256;
    const int ntt = 8 * (bj - bi + 1);           // total steps for the tile
    const int g0 = ch * CS;
    const int nt = min(CS, ntt - g0);            // 4..36 steps this chunk
    const bool direct = (cpt == 1);

    // subtile streams indexed by GLOBAL step g; zero page at triu edges
    const char* srcA0 = ws + (size_t)(offA(2 * bi)) * SUBT_B;
    const char* srcA1 = ws + (size_t)(offA(2 * bi + 1) - 4) * SUBT_B;
    const char* srcB0 = ws + WS_A + (size_t)(offB(2 * bj) + 8 * bi) * SUBT_B;
    const char* srcB1 = ws + WS_A + (size_t)(offB(2 * bj + 1) + 8 * bi) * SUBT_B;
    const char* zpage = ws + ZOFF;

    __shared__ __align__(16) char lds[4][4][SUBT_B];   // 128 KB, 4 buffers

    f32x4 acc[8][4];
    const f32x4 fz = {0.f, 0.f, 0.f, 0.f};
#pragma unroll
    for (int m = 0; m < 8; ++m)
#pragma unroll
        for (int n = 0; n < 4; ++n) acc[m][n] = fz;

    const int wv = tid >> 6;            // 0..7
    const int wvM = wv >> 2;            // 0..1: row half
    const int wvN = wv & 3;             // 0..3: col quarter
    const int lane = tid & 63;
    const int fr = lane & 15;
    const int gof = (lane >> 4) * 2048;
    const int cbase = (wvN & 1) * 64;

    auto stage = [&](int buf, int g) {  // 4 gll16 per thread
        const char* s0 = srcA0 + (size_t)g * SUBT_B;
        const char* s1 = (g >= 4) ? srcA1 + (size_t)g * SUBT_B : zpage;
        const char* s2 = (g < ntt - 4) ? srcB0 + (size_t)g * SUBT_B : zpage;
        const char* s3 = srcB1 + (size_t)g * SUBT_B;
        const int lo = wv * 1024 + lane * 16;
        char* d = &lds[buf][0][0] + wv * 1024;
        gll16(s0 + lo, d);
        gll16(s1 + lo, d + SUBT_B);
        gll16(s2 + lo, d + 2 * SUBT_B);
        gll16(s3 + lo, d + 3 * SUBT_B);
    };
    auto compute = [&](int buf) {
        const char* A_ = &lds[buf][wvM][0];
        const char* B_ = &lds[buf][2 + (wvN >> 1)][0];
        short8 af[8], bf[4];
#pragma unroll
        for (int m = 0; m < 8; ++m)
            af[m] = *reinterpret_cast<const short8*>(
                A_ + gof + (m * 16 + fr) * 16);
#pragma unroll
        for (int n = 0; n < 4; ++n)
            bf[n] = *reinterpret_cast<const short8*>(
                B_ + gof + (cbase + n * 16 + fr) * 16);
        __builtin_amdgcn_s_setprio(1);
#pragma unroll
        for (int m = 0; m < 8; ++m)
#pragma unroll
            for (int n = 0; n < 4; ++n)
                acc[m][n] = __builtin_amdgcn_mfma_f32_16x16x32_bf16(
                    af[m], bf[n], acc[m][n], 0, 0, 0);
        __builtin_amdgcn_s_setprio(0);
    };

    // ---- 4-buffer pipeline, 3 stages in flight (96 KB/CU) ----
    stage(0, g0);
    if (nt > 1) stage(1, g0 + 1);
    if (nt > 2) stage(2, g0 + 2);
    for (int t = 0; t < nt; ++t) {
        if (t + 2 < nt)
            asm volatile("s_waitcnt vmcnt(8)" ::: "memory");
        else if (t + 1 < nt)
            asm volatile("s_waitcnt vmcnt(4)" ::: "memory");
        else
            asm volatile("s_waitcnt vmcnt(0)" ::: "memory");
        __builtin_amdgcn_s_barrier();
        if (t + 3 < nt) stage((t + 3) & 3, g0 + t + 3);
        compute(t & 3);
    }

    if (direct) {
        // ---- direct masked store (tile may touch the diagonal) ----
#pragma unroll
        for (int m = 0; m < 8; ++m) {
            const int rbase = row0 + wvM * 128 + m * 16 + (lane >> 4) * 4;
#pragma unroll
            for (int n = 0; n < 4; ++n) {
                const int col = col0 + wvN * 64 + n * 16 + fr;
#pragma unroll
                for (int r = 0; r < 4; ++r) {
                    const int row = rbase + r;
                    C[(size_t)row * NDIM + col] =
                        (row <= col) ? acc[m][n][r] : 0.f;
                }
            }
        }
    } else {
        // ---- bf16 partial tile, row-major [256][256], slot = blockIdx ----
        char* po = part + (size_t)blockIdx.x * PART_B;
#pragma unroll
        for (int m = 0; m < 8; ++m) {
            const int rl = wvM * 128 + m * 16 + (lane >> 4) * 4;
#pragma unroll
            for (int n = 0; n < 4; ++n) {
                const int cl = wvN * 64 + n * 16 + fr;
#pragma unroll
                for (int r = 0; r < 4; ++r) {
                    const unsigned short us =
                        (unsigned short)(pkbf(acc[m][n][r], 0.f) & 0xffffu);
                    *reinterpret_cast<unsigned short*>(
                        po + (size_t)((rl + r) * 256 + cl) * 2) = us;
                }
            }
        }
    }
}

// ------- pass 3: sum bf16 partials -> C (78 tiles x 16 stripes) ------------
__global__ __launch_bounds__(256) void reduce_kernel(
    const char* __restrict__ part, float* __restrict__ C) {
    const int t = threadIdx.x;
    const int tile = blockIdx.x >> 4;            // 0..77
    const int stripe = blockIdx.x & 15;          // 16 rows each
    int bi, L, slot0, cpt;
    {
        int r = tile, sbase = 0;
        for (L = 16;; --L) {
            cpt = (8 * L + CS - 1) / CS;
            const int cnt = 17 - L;              // tiles at this L (all split)
            if (r < cnt) { bi = r; slot0 = sbase + r * cpt; break; }
            sbase += cnt * cpt;
            r -= cnt;
        }
    }
    const int bj = bi + L - 1;                   // L>=5 -> strictly upper
    const int row0 = bi * 256;
    const int col0 = bj * 256;

    const char* p0 = part + (size_t)slot0 * PART_B;
#pragma unroll
    for (int j = 0; j < 2; ++j) {
        const int g = stripe * 512 + j * 256 + t;   // 8-elem group 0..8191
        const size_t go = (size_t)g * 16;
        float s[8];
        const short8 v0 = *reinterpret_cast<const short8*>(p0 + go);
        const short8 v1 = *reinterpret_cast<const short8*>(p0 + PART_B + go);
#pragma unroll
        for (int k = 0; k < 8; ++k)
            s[k] = bf2f((unsigned short)v0[k]) + bf2f((unsigned short)v1[k]);
        if (cpt > 2) {
            const short8 v2 =
                *reinterpret_cast<const short8*>(p0 + 2 * PART_B + go);
#pragma unroll
            for (int k = 0; k < 8; ++k) s[k] += bf2f((unsigned short)v2[k]);
        }
        if (cpt > 3) {
            const short8 v3 =
                *reinterpret_cast<const short8*>(p0 + 3 * PART_B + go);
#pragma unroll
            for (int k = 0; k < 8; ++k) s[k] += bf2f((unsigned short)v3[k]);
        }
        const int rr = g >> 5;                   // 32 groups per 256-col row
        const int cc = (g & 31) * 8;
        float* dst = &C[(size_t)(row0 + rr) * NDIM + col0 + cc];
        *reinterpret_cast<f32x4*>(dst) = *reinterpret_cast<const f32x4*>(&s[0]);
        *reinterpret_cast<f32x4*>(dst + 4) =
            *reinterpret_cast<const f32x4*>(&s[4]);
    }
}

// ---------------- fallback (proven R3 kernel, no workspace) ----------------
#define FLSTR 80
#define NBLK 32
__device__ __forceinline__ int floff(int row, int kb) { return row * FLSTR + kb; }

__global__ __launch_bounds__(256) void trimm_fallback_kernel(
    const float* __restrict__ A, const float* __restrict__ B,
    float* __restrict__ C) {
    const int tid = threadIdx.x;
    const int id = blockIdx.x;
    int bi, bj;
    if (id >= 528) {
        int r = id - 528;
        int p = 1;
        while (r >= p) { r -= p; ++p; }
        bi = p; bj = r;
        const size_t base = (size_t)bi * 128 * NDIM + (size_t)bj * 128;
        const float4 z = make_float4(0.f, 0.f, 0.f, 0.f);
#pragma unroll
        for (int t = 0; t < 16; ++t) {
            const int f = tid + 256 * t;
            *reinterpret_cast<float4*>(
                &C[base + (size_t)(f >> 5) * NDIM + (f & 31) * 4]) = z;
        }
        return;
    }
    {
        int r = id, L = NBLK;
        while (r >= NBLK + 1 - L) { r -= NBLK + 1 - L; --L; }
        bi = r; bj = bi + L - 1;
    }
    const int row0 = bi * 128, col0 = bj * 128;
    __shared__ __align__(16) char lAs[128 * FLSTR];
    __shared__ __align__(16) char lBs[128 * FLSTR];
    f32x4 acc[4][4];
    const f32x4 fz = {0.f, 0.f, 0.f, 0.f};
#pragma unroll
    for (int m = 0; m < 4; ++m)
#pragma unroll
        for (int n = 0; n < 4; ++n) acc[m][n] = fz;
    const int wv = tid >> 6, wr = (wv >> 1) * 64, wc = (wv & 1) * 64;
    const int lane = tid & 63, fr = lane & 15, kb = (lane >> 4) * 16;
    const int bn = tid & 127, bkh = (tid >> 7) * 16;
    const int kendf = col0 + 128;
    for (int kt = row0; kt < kendf; kt += 32) {
        __syncthreads();
#pragma unroll
        for (int j = 0; j < 4; ++j) {
            const int f = tid + 256 * j;
            const int rr = f >> 3, kq = (f & 7) * 4;
            const float4 v = *reinterpret_cast<const float4*>(
                &A[(size_t)(row0 + rr) * NDIM + kt + kq]);
            uint2 w;
            w.x = pkbf(v.x, v.y); w.y = pkbf(v.z, v.w);
            *reinterpret_cast<uint2*>(lAs + floff(rr, kq * 2)) = w;
        }
        {
            float tv[16];
#pragma unroll
            for (int kk = 0; kk < 16; ++kk)
                tv[kk] = B[(size_t)(kt + bkh + kk) * NDIM + col0 + bn];
            uint4 w0, w1;
            w0.x = pkbf(tv[0], tv[1]);   w0.y = pkbf(tv[2], tv[3]);
            w0.z = pkbf(tv[4], tv[5]);   w0.w = pkbf(tv[6], tv[7]);
            w1.x = pkbf(tv[8], tv[9]);   w1.y = pkbf(tv[10], tv[11]);
            w1.z = pkbf(tv[12], tv[13]); w1.w = pkbf(tv[14], tv[15]);
            *reinterpret_cast<uint4*>(lBs + floff(bn, bkh * 2)) = w0;
            *reinterpret_cast<uint4*>(lBs + floff(bn, bkh * 2 + 16)) = w1;
        }
        __syncthreads();
        short8 af[4], bf[4];
#pragma unroll
        for (int m = 0; m < 4; ++m)
            af[m] = *reinterpret_cast<const short8*>(
                lAs + floff(wr + m * 16 + fr, kb));
#pragma unroll
        for (int n = 0; n < 4; ++n)
            bf[n] = *reinterpret_cast<const short8*>(
                lBs + floff(wc + n * 16 + fr, kb));
#pragma unroll
        for (int m = 0; m < 4; ++m)
#pragma unroll
            for (int n = 0; n < 4; ++n)
                acc[m][n] = __builtin_amdgcn_mfma_f32_16x16x32_bf16(
                    af[m], bf[n], acc[m][n], 0, 0, 0);
    }
#pragma unroll
    for (int m = 0; m < 4; ++m) {
        const int rbase = row0 + wr + m * 16 + (lane >> 4) * 4;
#pragma unroll
        for (int n = 0; n < 4; ++n) {
            const int col = col0 + wc + n * 16 + fr;
#pragma unroll
            for (int r = 0; r < 4; ++r) {
                const int row = rbase + r;
                C[(size_t)row * NDIM + col] = (row <= col) ? acc[m][n][r] : 0.f;
            }
        }
    }
}

extern "C" void kernel_launch(void* const* d_in, const int* in_sizes, int n_in,
                              void* d_out, int out_size, void* d_ws,
                              size_t ws_size, hipStream_t stream) {
    const float* A = (const float*)d_in[0];
    const float* B = (const float*)d_in[1];
    float* C = (float*)d_out;
    if (ws_size >= WS_NEED) {
        char* ws = (char*)d_ws;
        char* part = ws + POFF;
        prep_kernel<<<dim3(NZERO + 2 * NSUBT + 1), dim3(256), 0, stream>>>(
            A, B, C, ws);
        trimm256_kernel<<<dim3(NMAIN), dim3(512), 0, stream>>>(ws, C, part);
        reduce_kernel<<<dim3(NRED * 16), dim3(256), 0, stream>>>(part, C);
    } else {
        trimm_fallback_kernel<<<dim3(1024), dim3(256), 0, stream>>>(A, B, C);
    }
}

// Round 18
// 66.791 us; speedup vs baseline: 1.9312x; 1.0027x over previous
//
#include <hip/hip_runtime.h>
#include <hip/hip_bf16.h>

// C = triu( triu(A) @ triu(B) ), N=4096, fp32 in/out.
// Pass 1 (prep): zero strictly-lower 128-tiles of C + convert fp32->bf16 into
// TILED FRAGMENT-ORDER 128x32 subtiles in d_ws + 8KB zero page.
// Pass 2 (main): 256x256 tiles; K split into <=36-step chunks -> 248 blocks.
// 2 buffers x 64KB (two 32-k subtile sets), ONE vmcnt(0)+barrier per 64-k
// pair (R17 paid the sync event every 32-k step: ~1100 of 2630 cyc/step).
// Stage for pair p+1 issues right after pair p's barrier -> in flight a full
// compute (~2800 cyc) before its drain. global_load_lds staging, setprio
// around MFMA. L<=4 tiles: direct masked stores. L>=5: bf16 partials.
// Pass 3 (reduce): 78 tiles x 16 row-stripes = 1248 blocks.

#define NDIM 4096
#define SUBT_B 8192                        // one 128x32 bf16 subtile
#define NSUBT 2112                         // packed subtiles per matrix
#define WS_A ((size_t)NSUBT * SUBT_B)      // 17,301,504
#define WS_TOTAL (2 * WS_A)                // 34,603,008
#define ZOFF WS_TOTAL                      // 8KB zero page
#define POFF (WS_TOTAL + 8192)             // bf16 partial region
#define NSLOT 190                          // split chunk-blocks
#define PART_B 131072                      // 256x256 bf16 partial tile
#define WS_NEED (POFF + (size_t)NSLOT * PART_B)   // 59,514,880
#define NZERO 496                          // strictly-lower 128x128 tiles
#define NMAIN 248
#define NRED 78
#define CS 36                              // steps per chunk (even)

typedef __attribute__((ext_vector_type(8))) short short8;
typedef __attribute__((ext_vector_type(4))) float f32x4;

__device__ __forceinline__ unsigned pkbf(float a, float b) {
    __hip_bfloat162 h = __float22bfloat162_rn(make_float2(a, b));
    unsigned r;
    __builtin_memcpy(&r, &h, sizeof(r));
    return r;
}

__device__ __forceinline__ float bf2f(unsigned short us) {
    const unsigned u = ((unsigned)us) << 16;
    float f;
    __builtin_memcpy(&f, &u, 4);
    return f;
}

__device__ __forceinline__ void gll16(const void* g, void* l) {
    __builtin_amdgcn_global_load_lds(
        (const __attribute__((address_space(1))) unsigned int*)g,
        (__attribute__((address_space(3))) unsigned int*)l, 16, 0, 0);
}

__device__ __forceinline__ int offA(int p) { return 130 * p - 2 * p * p; }
__device__ __forceinline__ int offB(int q) { return 2 * q * (q + 1); }

// ---------------- pass 1: zero lower C tiles + convert/tile A,B + zpage -----
__global__ __launch_bounds__(256) void prep_kernel(
    const float* __restrict__ A, const float* __restrict__ B,
    float* __restrict__ C, char* __restrict__ ws) {
    const int t = threadIdx.x;
    int b = blockIdx.x;

    if (b < NZERO) {  // ---- zero one strictly-lower 128x128 tile of C ----
        int r = b, p = 1;
        while (r >= p) { r -= p; ++p; }
        const int bi = p, bj = r;          // bj < bi
        const size_t base = (size_t)bi * 128 * NDIM + (size_t)bj * 128;
        const float4 z = make_float4(0.f, 0.f, 0.f, 0.f);
#pragma unroll
        for (int j = 0; j < 16; ++j) {
            const int f = t + 256 * j;
            *reinterpret_cast<float4*>(
                &C[base + (size_t)(f >> 5) * NDIM + (f & 31) * 4]) = z;
        }
        return;
    }
    b -= NZERO;

    if (b < NSUBT) {  // ---- A subtile: [row][k] fp32 -> [g][row][16B] bf16 ----
        int bi = 0, rem = b;
        while (rem >= 128 - 4 * bi) { rem -= 128 - 4 * bi; ++bi; }
        const int kt32 = 4 * bi + rem;

        __shared__ __align__(16) char lsub[SUBT_B];
        const float* src = A + (size_t)(bi * 128) * NDIM + kt32 * 32;
#pragma unroll
        for (int j = 0; j < 4; ++j) {
            const int s4 = t + 256 * j;
            const int row = s4 >> 3;
            const int kf = (s4 & 7) * 4;
            const float4 v =
                *reinterpret_cast<const float4*>(src + (size_t)row * NDIM + kf);
            uint2 w;
            w.x = pkbf(v.x, v.y);
            w.y = pkbf(v.z, v.w);
            *reinterpret_cast<uint2*>(lsub + (kf >> 3) * 2048 + row * 16 +
                                      (kf & 4) * 2) = w;
        }
        __syncthreads();
        char* dst = ws + (size_t)b * SUBT_B;
#pragma unroll
        for (int j = 0; j < 2; ++j) {
            const int d = t + 256 * j;
            *reinterpret_cast<uint4*>(dst + d * 16) =
                *reinterpret_cast<const uint4*>(lsub + d * 16);
        }
        return;
    }
    b -= NSUBT;

    if (b < NSUBT) {  // ---- B subtile: [k][col] fp32 -> [g][col][16B] bf16 ----
        int bj = 0, rem = b;
        while (rem >= 4 * (bj + 1)) { rem -= 4 * (bj + 1); ++bj; }
        const int kt32 = rem;

        const int c = t & 127;
        const int kq = (t >> 7) * 16;
        const float* src = B + (size_t)(kt32 * 32 + kq) * NDIM + bj * 128 + c;
        float v[16];
#pragma unroll
        for (int i = 0; i < 16; ++i) v[i] = src[(size_t)i * NDIM];

        uint4 w0, w1;
        w0.x = pkbf(v[0], v[1]);   w0.y = pkbf(v[2], v[3]);
        w0.z = pkbf(v[4], v[5]);   w0.w = pkbf(v[6], v[7]);
        w1.x = pkbf(v[8], v[9]);   w1.y = pkbf(v[10], v[11]);
        w1.z = pkbf(v[12], v[13]); w1.w = pkbf(v[14], v[15]);

        char* dst = ws + WS_A + (size_t)b * SUBT_B + c * 16;
        const int g0 = kq >> 3;
        *reinterpret_cast<uint4*>(dst + g0 * 2048) = w0;
        *reinterpret_cast<uint4*>(dst + (g0 + 1) * 2048) = w1;
        return;
    }

    {  // ---- 8KB zero page ----
        uint4* zp = reinterpret_cast<uint4*>(ws + ZOFF);
        const uint4 z = {0u, 0u, 0u, 0u};
        zp[t] = z;
        zp[t + 256] = z;
    }
}

// ---------------- pass 2: 256x256 MFMA GEMM, chunked K ---------------------
__global__ __launch_bounds__(512) void trimm256_kernel(
    const char* __restrict__ ws, float* __restrict__ C,
    char* __restrict__ part) {
    const int tid = threadIdx.x;

    // decode (L desc, bi asc, ch asc): split chunks (L>=5) are ids 0..189
    int bi, bj, ch, cpt;
    {
        int r = blockIdx.x;
        int L = 16;
        for (;; --L) {
            cpt = (8 * L + CS - 1) / CS;
            const int cnt = (17 - L) * cpt;
            if (r < cnt) { bi = r / cpt; ch = r % cpt; break; }
            r -= cnt;
        }
        bj = bi + L - 1;
    }

    const int row0 = bi * 256;
    const int col0 = bj * 256;
    const int ntt = 8 * (bj - bi + 1);           // total steps for the tile
    const int g0 = ch * CS;
    const int nt = min(CS, ntt - g0);            // 4..36 steps (always even)
    const int gend = g0 + nt;
    const bool direct = (cpt == 1);

    // subtile streams indexed by GLOBAL step g; zero page at triu edges
    const char* srcA0 = ws + (size_t)(offA(2 * bi)) * SUBT_B;
    const char* srcA1 = ws + (size_t)(offA(2 * bi + 1) - 4) * SUBT_B;
    const char* srcB0 = ws + WS_A + (size_t)(offB(2 * bj) + 8 * bi) * SUBT_B;
    const char* srcB1 = ws + WS_A + (size_t)(offB(2 * bj + 1) + 8 * bi) * SUBT_B;
    const char* zpage = ws + ZOFF;

    __shared__ __align__(16) char lds[2][8][SUBT_B];   // 128 KB: 2 x 64KB

    f32x4 acc[8][4];
    const f32x4 fz = {0.f, 0.f, 0.f, 0.f};
#pragma unroll
    for (int m = 0; m < 8; ++m)
#pragma unroll
        for (int n = 0; n < 4; ++n) acc[m][n] = fz;

    const int wv = tid >> 6;            // 0..7
    const int wvM = wv >> 2;            // 0..1: row half
    const int wvN = wv & 3;             // 0..3: col quarter
    const int lane = tid & 63;
    const int fr = lane & 15;
    const int gof = (lane >> 4) * 2048;
    const int cbase = (wvN & 1) * 64;

    auto stage = [&](int buf, int half, int g) {  // 4 gll16 per thread
        const char* s0 = srcA0 + (size_t)g * SUBT_B;
        const char* s1 = (g >= 4) ? srcA1 + (size_t)g * SUBT_B : zpage;
        const char* s2 = (g < ntt - 4) ? srcB0 + (size_t)g * SUBT_B : zpage;
        const char* s3 = srcB1 + (size_t)g * SUBT_B;
        const int lo = wv * 1024 + lane * 16;
        char* d = &lds[buf][half * 4][0] + wv * 1024;
        gll16(s0 + lo, d);
        gll16(s1 + lo, d + SUBT_B);
        gll16(s2 + lo, d + 2 * SUBT_B);
        gll16(s3 + lo, d + 3 * SUBT_B);
    };
    auto stage2 = [&](int buf, int g) {           // both halves of a pair
        if (g < gend) stage(buf, 0, g);
        if (g + 1 < gend) stage(buf, 1, g + 1);
    };
    auto compute = [&](int buf, int half) {
        const char* A_ = &lds[buf][half * 4 + wvM][0];
        const char* B_ = &lds[buf][half * 4 + 2 + (wvN >> 1)][0];
        short8 af[8], bf[4];
#pragma unroll
        for (int m = 0; m < 8; ++m)
            af[m] = *reinterpret_cast<const short8*>(
                A_ + gof + (m * 16 + fr) * 16);
#pragma unroll
        for (int n = 0; n < 4; ++n)
            bf[n] = *reinterpret_cast<const short8*>(
                B_ + gof + (cbase + n * 16 + fr) * 16);
        __builtin_amdgcn_s_setprio(1);
#pragma unroll
        for (int m = 0; m < 8; ++m)
#pragma unroll
            for (int n = 0; n < 4; ++n)
                acc[m][n] = __builtin_amdgcn_mfma_f32_16x16x32_bf16(
                    af[m], bf[n], acc[m][n], 0, 0, 0);
        __builtin_amdgcn_s_setprio(0);
    };

    // ---- 2x64KB pipeline: one vmcnt(0)+barrier per 64-k pair ----
    stage2(0, g0);                                // prologue: pair 0
    const int npair = nt >> 1;                    // nt is always even
    for (int p = 0; p < npair; ++p) {
        // drains the stage issued one full pair (~2 computes) earlier
        asm volatile("s_waitcnt vmcnt(0)" ::: "memory");
        __builtin_amdgcn_s_barrier();
        if (p + 1 < npair) stage2((p + 1) & 1, g0 + 2 * (p + 1));
        compute(p & 1, 0);
        compute(p & 1, 1);
    }

    if (direct) {
        // ---- direct masked store (tile may touch the diagonal) ----
#pragma unroll
        for (int m = 0; m < 8; ++m) {
            const int rbase = row0 + wvM * 128 + m * 16 + (lane >> 4) * 4;
#pragma unroll
            for (int n = 0; n < 4; ++n) {
                const int col = col0 + wvN * 64 + n * 16 + fr;
#pragma unroll
                for (int r = 0; r < 4; ++r) {
                    const int row = rbase + r;
                    C[(size_t)row * NDIM + col] =
                        (row <= col) ? acc[m][n][r] : 0.f;
                }
            }
        }
    } else {
        // ---- bf16 partial tile, row-major [256][256], slot = blockIdx ----
        char* po = part + (size_t)blockIdx.x * PART_B;
#pragma unroll
        for (int m = 0; m < 8; ++m) {
            const int rl = wvM * 128 + m * 16 + (lane >> 4) * 4;
#pragma unroll
            for (int n = 0; n < 4; ++n) {
                const int cl = wvN * 64 + n * 16 + fr;
#pragma unroll
                for (int r = 0; r < 4; ++r) {
                    const unsigned short us =
                        (unsigned short)(pkbf(acc[m][n][r], 0.f) & 0xffffu);
                    *reinterpret_cast<unsigned short*>(
                        po + (size_t)((rl + r) * 256 + cl) * 2) = us;
                }
            }
        }
    }
}

// ------- pass 3: sum bf16 partials -> C (78 tiles x 16 stripes) ------------
__global__ __launch_bounds__(256) void reduce_kernel(
    const char* __restrict__ part, float* __restrict__ C) {
    const int t = threadIdx.x;
    const int tile = blockIdx.x >> 4;            // 0..77
    const int stripe = blockIdx.x & 15;          // 16 rows each
    int bi, L, slot0, cpt;
    {
        int r = tile, sbase = 0;
        for (L = 16;; --L) {
            cpt = (8 * L + CS - 1) / CS;
            const int cnt = 17 - L;              // tiles at this L (all split)
            if (r < cnt) { bi = r; slot0 = sbase + r * cpt; break; }
            sbase += cnt * cpt;
            r -= cnt;
        }
    }
    const int bj = bi + L - 1;                   // L>=5 -> strictly upper
    const int row0 = bi * 256;
    const int col0 = bj * 256;

    const char* p0 = part + (size_t)slot0 * PART_B;
#pragma unroll
    for (int j = 0; j < 2; ++j) {
        const int g = stripe * 512 + j * 256 + t;   // 8-elem group 0..8191
        const size_t go = (size_t)g * 16;
        float s[8];
        const short8 v0 = *reinterpret_cast<const short8*>(p0 + go);
        const short8 v1 = *reinterpret_cast<const short8*>(p0 + PART_B + go);
#pragma unroll
        for (int k = 0; k < 8; ++k)
            s[k] = bf2f((unsigned short)v0[k]) + bf2f((unsigned short)v1[k]);
        if (cpt > 2) {
            const short8 v2 =
                *reinterpret_cast<const short8*>(p0 + 2 * PART_B + go);
#pragma unroll
            for (int k = 0; k < 8; ++k) s[k] += bf2f((unsigned short)v2[k]);
        }
        if (cpt > 3) {
            const short8 v3 =
                *reinterpret_cast<const short8*>(p0 + 3 * PART_B + go);
#pragma unroll
            for (int k = 0; k < 8; ++k) s[k] += bf2f((unsigned short)v3[k]);
        }
        const int rr = g >> 5;                   // 32 groups per 256-col row
        const int cc = (g & 31) * 8;
        float* dst = &C[(size_t)(row0 + rr) * NDIM + col0 + cc];
        *reinterpret_cast<f32x4*>(dst) = *reinterpret_cast<const f32x4*>(&s[0]);
        *reinterpret_cast<f32x4*>(dst + 4) =
            *reinterpret_cast<const f32x4*>(&s[4]);
    }
}

// ---------------- fallback (proven R3 kernel, no workspace) ----------------
#define FLSTR 80
#define NBLK 32
__device__ __forceinline__ int floff(int row, int kb) { return row * FLSTR + kb; }

__global__ __launch_bounds__(256) void trimm_fallback_kernel(
    const float* __restrict__ A, const float* __restrict__ B,
    float* __restrict__ C) {
    const int tid = threadIdx.x;
    const int id = blockIdx.x;
    int bi, bj;
    if (id >= 528) {
        int r = id - 528;
        int p = 1;
        while (r >= p) { r -= p; ++p; }
        bi = p; bj = r;
        const size_t base = (size_t)bi * 128 * NDIM + (size_t)bj * 128;
        const float4 z = make_float4(0.f, 0.f, 0.f, 0.f);
#pragma unroll
        for (int t = 0; t < 16; ++t) {
            const int f = tid + 256 * t;
            *reinterpret_cast<float4*>(
                &C[base + (size_t)(f >> 5) * NDIM + (f & 31) * 4]) = z;
        }
        return;
    }
    {
        int r = id, L = NBLK;
        while (r >= NBLK + 1 - L) { r -= NBLK + 1 - L; --L; }
        bi = r; bj = bi + L - 1;
    }
    const int row0 = bi * 128, col0 = bj * 128;
    __shared__ __align__(16) char lAs[128 * FLSTR];
    __shared__ __align__(16) char lBs[128 * FLSTR];
    f32x4 acc[4][4];
    const f32x4 fz = {0.f, 0.f, 0.f, 0.f};
#pragma unroll
    for (int m = 0; m < 4; ++m)
#pragma unroll
        for (int n = 0; n < 4; ++n) acc[m][n] = fz;
    const int wv = tid >> 6, wr = (wv >> 1) * 64, wc = (wv & 1) * 64;
    const int lane = tid & 63, fr = lane & 15, kb = (lane >> 4) * 16;
    const int bn = tid & 127, bkh = (tid >> 7) * 16;
    const int kendf = col0 + 128;
    for (int kt = row0; kt < kendf; kt += 32) {
        __syncthreads();
#pragma unroll
        for (int j = 0; j < 4; ++j) {
            const int f = tid + 256 * j;
            const int rr = f >> 3, kq = (f & 7) * 4;
            const float4 v = *reinterpret_cast<const float4*>(
                &A[(size_t)(row0 + rr) * NDIM + kt + kq]);
            uint2 w;
            w.x = pkbf(v.x, v.y); w.y = pkbf(v.z, v.w);
            *reinterpret_cast<uint2*>(lAs + floff(rr, kq * 2)) = w;
        }
        {
            float tv[16];
#pragma unroll
            for (int kk = 0; kk < 16; ++kk)
                tv[kk] = B[(size_t)(kt + bkh + kk) * NDIM + col0 + bn];
            uint4 w0, w1;
            w0.x = pkbf(tv[0], tv[1]);   w0.y = pkbf(tv[2], tv[3]);
            w0.z = pkbf(tv[4], tv[5]);   w0.w = pkbf(tv[6], tv[7]);
            w1.x = pkbf(tv[8], tv[9]);   w1.y = pkbf(tv[10], tv[11]);
            w1.z = pkbf(tv[12], tv[13]); w1.w = pkbf(tv[14], tv[15]);
            *reinterpret_cast<uint4*>(lBs + floff(bn, bkh * 2)) = w0;
            *reinterpret_cast<uint4*>(lBs + floff(bn, bkh * 2 + 16)) = w1;
        }
        __syncthreads();
        short8 af[4], bf[4];
#pragma unroll
        for (int m = 0; m < 4; ++m)
            af[m] = *reinterpret_cast<const short8*>(
                lAs + floff(wr + m * 16 + fr, kb));
#pragma unroll
        for (int n = 0; n < 4; ++n)
            bf[n] = *reinterpret_cast<const short8*>(
                lBs + floff(wc + n * 16 + fr, kb));
#pragma unroll
        for (int m = 0; m < 4; ++m)
#pragma unroll
            for (int n = 0; n < 4; ++n)
                acc[m][n] = __builtin_amdgcn_mfma_f32_16x16x32_bf16(
                    af[m], bf[n], acc[m][n], 0, 0, 0);
    }
#pragma unroll
    for (int m = 0; m < 4; ++m) {
        const int rbase = row0 + wr + m * 16 + (lane >> 4) * 4;
#pragma unroll
        for (int n = 0; n < 4; ++n) {
            const int col = col0 + wc + n * 16 + fr;
#pragma unroll
            for (int r = 0; r < 4; ++r) {
                const int row = rbase + r;
                C[(size_t)row * NDIM + col] = (row <= col) ? acc[m][n][r] : 0.f;
            }
        }
    }
}

extern "C" void kernel_launch(void* const* d_in, const int* in_sizes, int n_in,
                              void* d_out, int out_size, void* d_ws,
                              size_t ws_size, hipStream_t stream) {
    const float* A = (const float*)d_in[0];
    const float* B = (const float*)d_in[1];
    float* C = (float*)d_out;
    if (ws_size >= WS_NEED) {
        char* ws = (char*)d_ws;
        char* part = ws + POFF;
        prep_kernel<<<dim3(NZERO + 2 * NSUBT + 1), dim3(256), 0, stream>>>(
            A, B, C, ws);
        trimm256_kernel<<<dim3(NMAIN), dim3(512), 0, stream>>>(ws, C, part);
        reduce_kernel<<<dim3(NRED * 16), dim3(256), 0, stream>>>(part, C);
    } else {
        trimm_fallback_kernel<<<dim3(1024), dim3(256), 0, stream>>>(A, B, C);
    }
}

// Round 19
// 66.650 us; speedup vs baseline: 1.9353x; 1.0021x over previous
//
#include <hip/hip_runtime.h>
#include <hip/hip_bf16.h>

// C = triu( triu(A) @ triu(B) ), N=4096, fp32 in/out.
// Pass 1 (prep): zero strictly-lower 128-tiles of C + convert fp32->bf16 into
// TILED FRAGMENT-ORDER 128x32 subtiles in d_ws + 8KB zero page.
// Pass 2 (main): 256x256 tiles; K split into <=36-step chunks -> 248 blocks.
// 2 buffers x 64KB. m201-style phase interleave: each K32-half is 2 clusters
// of {frag ds_reads + 2 gll16 -> barrier -> setprio + 16 MFMA}; cluster k's
// async MFMAs overlap cluster k+1's ds_reads (LDS and matrix pipes both fed,
// vs R17/R18's read-burst-then-MFMA-burst at 2630 cyc/step). One vmcnt(0) +
// barrier per 64-k pair. L<=4 tiles: direct masked stores. L>=5: bf16
// partials. Pass 3 (reduce): 78 tiles x 16 row-stripes.

#define NDIM 4096
#define SUBT_B 8192                        // one 128x32 bf16 subtile
#define NSUBT 2112                         // packed subtiles per matrix
#define WS_A ((size_t)NSUBT * SUBT_B)      // 17,301,504
#define WS_TOTAL (2 * WS_A)                // 34,603,008
#define ZOFF WS_TOTAL                      // 8KB zero page
#define POFF (WS_TOTAL + 8192)             // bf16 partial region
#define NSLOT 190                          // split chunk-blocks
#define PART_B 131072                      // 256x256 bf16 partial tile
#define WS_NEED (POFF + (size_t)NSLOT * PART_B)   // 59,514,880
#define NZERO 496                          // strictly-lower 128x128 tiles
#define NMAIN 248
#define NRED 78
#define CS 36                              // steps per chunk (even)

typedef __attribute__((ext_vector_type(8))) short short8;
typedef __attribute__((ext_vector_type(4))) float f32x4;

__device__ __forceinline__ unsigned pkbf(float a, float b) {
    __hip_bfloat162 h = __float22bfloat162_rn(make_float2(a, b));
    unsigned r;
    __builtin_memcpy(&r, &h, sizeof(r));
    return r;
}

__device__ __forceinline__ float bf2f(unsigned short us) {
    const unsigned u = ((unsigned)us) << 16;
    float f;
    __builtin_memcpy(&f, &u, 4);
    return f;
}

__device__ __forceinline__ void gll16(const void* g, void* l) {
    __builtin_amdgcn_global_load_lds(
        (const __attribute__((address_space(1))) unsigned int*)g,
        (__attribute__((address_space(3))) unsigned int*)l, 16, 0, 0);
}

__device__ __forceinline__ int offA(int p) { return 130 * p - 2 * p * p; }
__device__ __forceinline__ int offB(int q) { return 2 * q * (q + 1); }

// ---------------- pass 1: zero lower C tiles + convert/tile A,B + zpage -----
__global__ __launch_bounds__(256) void prep_kernel(
    const float* __restrict__ A, const float* __restrict__ B,
    float* __restrict__ C, char* __restrict__ ws) {
    const int t = threadIdx.x;
    int b = blockIdx.x;

    if (b < NZERO) {  // ---- zero one strictly-lower 128x128 tile of C ----
        int r = b, p = 1;
        while (r >= p) { r -= p; ++p; }
        const int bi = p, bj = r;          // bj < bi
        const size_t base = (size_t)bi * 128 * NDIM + (size_t)bj * 128;
        const float4 z = make_float4(0.f, 0.f, 0.f, 0.f);
#pragma unroll
        for (int j = 0; j < 16; ++j) {
            const int f = t + 256 * j;
            *reinterpret_cast<float4*>(
                &C[base + (size_t)(f >> 5) * NDIM + (f & 31) * 4]) = z;
        }
        return;
    }
    b -= NZERO;

    if (b < NSUBT) {  // ---- A subtile: [row][k] fp32 -> [g][row][16B] bf16 ----
        int bi = 0, rem = b;
        while (rem >= 128 - 4 * bi) { rem -= 128 - 4 * bi; ++bi; }
        const int kt32 = 4 * bi + rem;

        __shared__ __align__(16) char lsub[SUBT_B];
        const float* src = A + (size_t)(bi * 128) * NDIM + kt32 * 32;
#pragma unroll
        for (int j = 0; j < 4; ++j) {
            const int s4 = t + 256 * j;
            const int row = s4 >> 3;
            const int kf = (s4 & 7) * 4;
            const float4 v =
                *reinterpret_cast<const float4*>(src + (size_t)row * NDIM + kf);
            uint2 w;
            w.x = pkbf(v.x, v.y);
            w.y = pkbf(v.z, v.w);
            *reinterpret_cast<uint2*>(lsub + (kf >> 3) * 2048 + row * 16 +
                                      (kf & 4) * 2) = w;
        }
        __syncthreads();
        char* dst = ws + (size_t)b * SUBT_B;
#pragma unroll
        for (int j = 0; j < 2; ++j) {
            const int d = t + 256 * j;
            *reinterpret_cast<uint4*>(dst + d * 16) =
                *reinterpret_cast<const uint4*>(lsub + d * 16);
        }
        return;
    }
    b -= NSUBT;

    if (b < NSUBT) {  // ---- B subtile: [k][col] fp32 -> [g][col][16B] bf16 ----
        int bj = 0, rem = b;
        while (rem >= 4 * (bj + 1)) { rem -= 4 * (bj + 1); ++bj; }
        const int kt32 = rem;

        const int c = t & 127;
        const int kq = (t >> 7) * 16;
        const float* src = B + (size_t)(kt32 * 32 + kq) * NDIM + bj * 128 + c;
        float v[16];
#pragma unroll
        for (int i = 0; i < 16; ++i) v[i] = src[(size_t)i * NDIM];

        uint4 w0, w1;
        w0.x = pkbf(v[0], v[1]);   w0.y = pkbf(v[2], v[3]);
        w0.z = pkbf(v[4], v[5]);   w0.w = pkbf(v[6], v[7]);
        w1.x = pkbf(v[8], v[9]);   w1.y = pkbf(v[10], v[11]);
        w1.z = pkbf(v[12], v[13]); w1.w = pkbf(v[14], v[15]);

        char* dst = ws + WS_A + (size_t)b * SUBT_B + c * 16;
        const int g0 = kq >> 3;
        *reinterpret_cast<uint4*>(dst + g0 * 2048) = w0;
        *reinterpret_cast<uint4*>(dst + (g0 + 1) * 2048) = w1;
        return;
    }

    {  // ---- 8KB zero page ----
        uint4* zp = reinterpret_cast<uint4*>(ws + ZOFF);
        const uint4 z = {0u, 0u, 0u, 0u};
        zp[t] = z;
        zp[t + 256] = z;
    }
}

// ---------------- pass 2: 256x256 MFMA GEMM, chunked K ---------------------
__global__ __launch_bounds__(512) void trimm256_kernel(
    const char* __restrict__ ws, float* __restrict__ C,
    char* __restrict__ part) {
    const int tid = threadIdx.x;

    // decode (L desc, bi asc, ch asc): split chunks (L>=5) are ids 0..189
    int bi, bj, ch, cpt;
    {
        int r = blockIdx.x;
        int L = 16;
        for (;; --L) {
            cpt = (8 * L + CS - 1) / CS;
            const int cnt = (17 - L) * cpt;
            if (r < cnt) { bi = r / cpt; ch = r % cpt; break; }
            r -= cnt;
        }
        bj = bi + L - 1;
    }

    const int row0 = bi * 256;
    const int col0 = bj * 256;
    const int ntt = 8 * (bj - bi + 1);           // total steps for the tile
    const int g0 = ch * CS;
    const int nt = min(CS, ntt - g0);            // 4..36 steps (always even)
    const int gend = g0 + nt;
    const bool direct = (cpt == 1);

    // subtile streams indexed by GLOBAL step g; zero page at triu edges
    const char* srcA0 = ws + (size_t)(offA(2 * bi)) * SUBT_B;
    const char* srcA1 = ws + (size_t)(offA(2 * bi + 1) - 4) * SUBT_B;
    const char* srcB0 = ws + WS_A + (size_t)(offB(2 * bj) + 8 * bi) * SUBT_B;
    const char* srcB1 = ws + WS_A + (size_t)(offB(2 * bj + 1) + 8 * bi) * SUBT_B;
    const char* zpage = ws + ZOFF;

    __shared__ __align__(16) char lds[2][8][SUBT_B];   // 128 KB: 2 x 64KB

    f32x4 acc[8][4];
    const f32x4 fz = {0.f, 0.f, 0.f, 0.f};
#pragma unroll
    for (int m = 0; m < 8; ++m)
#pragma unroll
        for (int n = 0; n < 4; ++n) acc[m][n] = fz;

    const int wv = tid >> 6;            // 0..7
    const int wvM = wv >> 2;            // 0..1: row half
    const int wvN = wv & 3;             // 0..3: col quarter
    const int lane = tid & 63;
    const int fr = lane & 15;
    const int gof = (lane >> 4) * 2048;
    const int cbase = (wvN & 1) * 64;
    const int lo = wv * 1024 + lane * 16;

    // one subtile s of step g into lds[buf][half*4+s]
    auto stage1 = [&](int buf, int half, int s, int g) {
        const char* src;
        if (s == 0)      src = srcA0 + (size_t)g * SUBT_B;
        else if (s == 1) src = (g >= 4) ? srcA1 + (size_t)g * SUBT_B : zpage;
        else if (s == 2) src = (g < ntt - 4) ? srcB0 + (size_t)g * SUBT_B : zpage;
        else             src = srcB1 + (size_t)g * SUBT_B;
        gll16(src + lo, &lds[buf][half * 4 + s][0] + wv * 1024);
    };
    auto stage_pair = [&](int buf, int g) {       // prologue: full pair
#pragma unroll
        for (int half = 0; half < 2; ++half)
#pragma unroll
            for (int s = 0; s < 4; ++s)
                if (g + half < gend) stage1(buf, half, s, g + half);
    };

    // ---- pipeline: vmcnt(0)+bar per pair; 4 interleaved clusters/pair ----
    stage_pair(0, g0);
    const int npair = nt >> 1;
    for (int p = 0; p < npair; ++p) {
        asm volatile("s_waitcnt vmcnt(0)" ::: "memory");
        __builtin_amdgcn_s_barrier();
        const int buf = p & 1;
        const bool st = (p + 1 < npair);
        const int gn = g0 + 2 * (p + 1);
#pragma unroll
        for (int half = 0; half < 2; ++half) {
            const char* A_ = &lds[buf][half * 4 + wvM][0];
            const char* B_ = &lds[buf][half * 4 + 2 + (wvN >> 1)][0];
            short8 bf[4], af[4];
            // ---- cluster 0: B frags + A rows 0..3, stage A-subtiles ----
#pragma unroll
            for (int n = 0; n < 4; ++n)
                bf[n] = *reinterpret_cast<const short8*>(
                    B_ + gof + (cbase + n * 16 + fr) * 16);
#pragma unroll
            for (int m = 0; m < 4; ++m)
                af[m] = *reinterpret_cast<const short8*>(
                    A_ + gof + (m * 16 + fr) * 16);
            if (st) {
                stage1(buf ^ 1, half, 0, gn + half);
                stage1(buf ^ 1, half, 1, gn + half);
            }
            __builtin_amdgcn_s_barrier();
            __builtin_amdgcn_s_setprio(1);
#pragma unroll
            for (int m = 0; m < 4; ++m)
#pragma unroll
                for (int n = 0; n < 4; ++n)
                    acc[m][n] = __builtin_amdgcn_mfma_f32_16x16x32_bf16(
                        af[m], bf[n], acc[m][n], 0, 0, 0);
            __builtin_amdgcn_s_setprio(0);
            // ---- cluster 1: A rows 4..7 (MFMAs above still in flight) ----
#pragma unroll
            for (int m = 0; m < 4; ++m)
                af[m] = *reinterpret_cast<const short8*>(
                    A_ + gof + ((m + 4) * 16 + fr) * 16);
            if (st) {
                stage1(buf ^ 1, half, 2, gn + half);
                stage1(buf ^ 1, half, 3, gn + half);
            }
            __builtin_amdgcn_s_barrier();
            __builtin_amdgcn_s_setprio(1);
#pragma unroll
            for (int m = 0; m < 4; ++m)
#pragma unroll
                for (int n = 0; n < 4; ++n)
                    acc[m + 4][n] = __builtin_amdgcn_mfma_f32_16x16x32_bf16(
                        af[m], bf[n], acc[m + 4][n], 0, 0, 0);
            __builtin_amdgcn_s_setprio(0);
        }
    }

    if (direct) {
        // ---- direct masked store (tile may touch the diagonal) ----
#pragma unroll
        for (int m = 0; m < 8; ++m) {
            const int rbase = row0 + wvM * 128 + m * 16 + (lane >> 4) * 4;
#pragma unroll
            for (int n = 0; n < 4; ++n) {
                const int col = col0 + wvN * 64 + n * 16 + fr;
#pragma unroll
                for (int r = 0; r < 4; ++r) {
                    const int row = rbase + r;
                    C[(size_t)row * NDIM + col] =
                        (row <= col) ? acc[m][n][r] : 0.f;
                }
            }
        }
    } else {
        // ---- bf16 partial tile, row-major [256][256], slot = blockIdx ----
        char* po = part + (size_t)blockIdx.x * PART_B;
#pragma unroll
        for (int m = 0; m < 8; ++m) {
            const int rl = wvM * 128 + m * 16 + (lane >> 4) * 4;
#pragma unroll
            for (int n = 0; n < 4; ++n) {
                const int cl = wvN * 64 + n * 16 + fr;
#pragma unroll
                for (int r = 0; r < 4; ++r) {
                    const unsigned short us =
                        (unsigned short)(pkbf(acc[m][n][r], 0.f) & 0xffffu);
                    *reinterpret_cast<unsigned short*>(
                        po + (size_t)((rl + r) * 256 + cl) * 2) = us;
                }
            }
        }
    }
}

// ------- pass 3: sum bf16 partials -> C (78 tiles x 16 stripes) ------------
__global__ __launch_bounds__(256) void reduce_kernel(
    const char* __restrict__ part, float* __restrict__ C) {
    const int t = threadIdx.x;
    const int tile = blockIdx.x >> 4;            // 0..77
    const int stripe = blockIdx.x & 15;          // 16 rows each
    int bi, L, slot0, cpt;
    {
        int r = tile, sbase = 0;
        for (L = 16;; --L) {
            cpt = (8 * L + CS - 1) / CS;
            const int cnt = 17 - L;              // tiles at this L (all split)
            if (r < cnt) { bi = r; slot0 = sbase + r * cpt; break; }
            sbase += cnt * cpt;
            r -= cnt;
        }
    }
    const int bj = bi + L - 1;                   // L>=5 -> strictly upper
    const int row0 = bi * 256;
    const int col0 = bj * 256;

    const char* p0 = part + (size_t)slot0 * PART_B;
#pragma unroll
    for (int j = 0; j < 2; ++j) {
        const int g = stripe * 512 + j * 256 + t;   // 8-elem group 0..8191
        const size_t go = (size_t)g * 16;
        float s[8];
        const short8 v0 = *reinterpret_cast<const short8*>(p0 + go);
        const short8 v1 = *reinterpret_cast<const short8*>(p0 + PART_B + go);
#pragma unroll
        for (int k = 0; k < 8; ++k)
            s[k] = bf2f((unsigned short)v0[k]) + bf2f((unsigned short)v1[k]);
        if (cpt > 2) {
            const short8 v2 =
                *reinterpret_cast<const short8*>(p0 + 2 * PART_B + go);
#pragma unroll
            for (int k = 0; k < 8; ++k) s[k] += bf2f((unsigned short)v2[k]);
        }
        if (cpt > 3) {
            const short8 v3 =
                *reinterpret_cast<const short8*>(p0 + 3 * PART_B + go);
#pragma unroll
            for (int k = 0; k < 8; ++k) s[k] += bf2f((unsigned short)v3[k]);
        }
        const int rr = g >> 5;                   // 32 groups per 256-col row
        const int cc = (g & 31) * 8;
        float* dst = &C[(size_t)(row0 + rr) * NDIM + col0 + cc];
        *reinterpret_cast<f32x4*>(dst) = *reinterpret_cast<const f32x4*>(&s[0]);
        *reinterpret_cast<f32x4*>(dst + 4) =
            *reinterpret_cast<const f32x4*>(&s[4]);
    }
}

// ---------------- fallback (proven R3 kernel, no workspace) ----------------
#define FLSTR 80
#define NBLK 32
__device__ __forceinline__ int floff(int row, int kb) { return row * FLSTR + kb; }

__global__ __launch_bounds__(256) void trimm_fallback_kernel(
    const float* __restrict__ A, const float* __restrict__ B,
    float* __restrict__ C) {
    const int tid = threadIdx.x;
    const int id = blockIdx.x;
    int bi, bj;
    if (id >= 528) {
        int r = id - 528;
        int p = 1;
        while (r >= p) { r -= p; ++p; }
        bi = p; bj = r;
        const size_t base = (size_t)bi * 128 * NDIM + (size_t)bj * 128;
        const float4 z = make_float4(0.f, 0.f, 0.f, 0.f);
#pragma unroll
        for (int t = 0; t < 16; ++t) {
            const int f = tid + 256 * t;
            *reinterpret_cast<float4*>(
                &C[base + (size_t)(f >> 5) * NDIM + (f & 31) * 4]) = z;
        }
        return;
    }
    {
        int r = id, L = NBLK;
        while (r >= NBLK + 1 - L) { r -= NBLK + 1 - L; --L; }
        bi = r; bj = bi + L - 1;
    }
    const int row0 = bi * 128, col0 = bj * 128;
    __shared__ __align__(16) char lAs[128 * FLSTR];
    __shared__ __align__(16) char lBs[128 * FLSTR];
    f32x4 acc[4][4];
    const f32x4 fz = {0.f, 0.f, 0.f, 0.f};
#pragma unroll
    for (int m = 0; m < 4; ++m)
#pragma unroll
        for (int n = 0; n < 4; ++n) acc[m][n] = fz;
    const int wv = tid >> 6, wr = (wv >> 1) * 64, wc = (wv & 1) * 64;
    const int lane = tid & 63, fr = lane & 15, kb = (lane >> 4) * 16;
    const int bn = tid & 127, bkh = (tid >> 7) * 16;
    const int kendf = col0 + 128;
    for (int kt = row0; kt < kendf; kt += 32) {
        __syncthreads();
#pragma unroll
        for (int j = 0; j < 4; ++j) {
            const int f = tid + 256 * j;
            const int rr = f >> 3, kq = (f & 7) * 4;
            const float4 v = *reinterpret_cast<const float4*>(
                &A[(size_t)(row0 + rr) * NDIM + kt + kq]);
            uint2 w;
            w.x = pkbf(v.x, v.y); w.y = pkbf(v.z, v.w);
            *reinterpret_cast<uint2*>(lAs + floff(rr, kq * 2)) = w;
        }
        {
            float tv[16];
#pragma unroll
            for (int kk = 0; kk < 16; ++kk)
                tv[kk] = B[(size_t)(kt + bkh + kk) * NDIM + col0 + bn];
            uint4 w0, w1;
            w0.x = pkbf(tv[0], tv[1]);   w0.y = pkbf(tv[2], tv[3]);
            w0.z = pkbf(tv[4], tv[5]);   w0.w = pkbf(tv[6], tv[7]);
            w1.x = pkbf(tv[8], tv[9]);   w1.y = pkbf(tv[10], tv[11]);
            w1.z = pkbf(tv[12], tv[13]); w1.w = pkbf(tv[14], tv[15]);
            *reinterpret_cast<uint4*>(lBs + floff(bn, bkh * 2)) = w0;
            *reinterpret_cast<uint4*>(lBs + floff(bn, bkh * 2 + 16)) = w1;
        }
        __syncthreads();
        short8 af[4], bf[4];
#pragma unroll
        for (int m = 0; m < 4; ++m)
            af[m] = *reinterpret_cast<const short8*>(
                lAs + floff(wr + m * 16 + fr, kb));
#pragma unroll
        for (int n = 0; n < 4; ++n)
            bf[n] = *reinterpret_cast<const short8*>(
                lBs + floff(wc + n * 16 + fr, kb));
#pragma unroll
        for (int m = 0; m < 4; ++m)
#pragma unroll
            for (int n = 0; n < 4; ++n)
                acc[m][n] = __builtin_amdgcn_mfma_f32_16x16x32_bf16(
                    af[m], bf[n], acc[m][n], 0, 0, 0);
    }
#pragma unroll
    for (int m = 0; m < 4; ++m) {
        const int rbase = row0 + wr + m * 16 + (lane >> 4) * 4;
#pragma unroll
        for (int n = 0; n < 4; ++n) {
            const int col = col0 + wc + n * 16 + fr;
#pragma unroll
            for (int r = 0; r < 4; ++r) {
                const int row = rbase + r;
                C[(size_t)row * NDIM + col] = (row <= col) ? acc[m][n][r] : 0.f;
            }
        }
    }
}

extern "C" void kernel_launch(void* const* d_in, const int* in_sizes, int n_in,
                              void* d_out, int out_size, void* d_ws,
                              size_t ws_size, hipStream_t stream) {
    const float* A = (const float*)d_in[0];
    const float* B = (const float*)d_in[1];
    float* C = (float*)d_out;
    if (ws_size >= WS_NEED) {
        char* ws = (char*)d_ws;
        char* part = ws + POFF;
        prep_kernel<<<dim3(NZERO + 2 * NSUBT + 1), dim3(256), 0, stream>>>(
            A, B, C, ws);
        trimm256_kernel<<<dim3(NMAIN), dim3(512), 0, stream>>>(ws, C, part);
        reduce_kernel<<<dim3(NRED * 16), dim3(256), 0, stream>>>(part, C);
    } else {
        trimm_fallback_kernel<<<dim3(1024), dim3(256), 0, stream>>>(A, B, C);
    }
}